// Round 12
// baseline (201.939 us; speedup 1.0000x reference)
//
#include <hip/hip_runtime.h>
#include <hip/hip_bf16.h>
#include <math.h>

// Problem constants
#define BSZ     2
#define LLEN    1024
#define DM      1024
#define DI      2048
#define DS      16
#define DTR     128
#define NXP     160          // DTR + 2*DS
#define MROWS   (BSZ*LLEN)   // 2048
#define NCH     32           // scan chunks
#define CHL     (LLEN/NCH)   // 32 steps per chunk

typedef short  bf16x8 __attribute__((ext_vector_type(8)));   // 8 bf16 (4 VGPRs)
typedef float  f32x4  __attribute__((ext_vector_type(4)));

__device__ __forceinline__ unsigned short f2bf(float f) {
    unsigned int u = __float_as_uint(f);
    return (unsigned short)((u + 0x7FFFu + ((u >> 16) & 1u)) >> 16);   // RNE
}
__device__ __forceinline__ float bf2f(unsigned short u) {
    return __uint_as_float((unsigned int)u << 16);
}

// async 16B/lane global->LDS copy (wave-uniform LDS base + lane*16)
__device__ __forceinline__ void gload_lds16(const void* g, void* lds) {
    __builtin_amdgcn_global_load_lds(
        (const __attribute__((address_space(1))) void*)g,
        (__attribute__((address_space(3))) void*)lds, 16, 0, 0);
}

// ---------------------------------------------------------------------------
// prep: ONE dispatch = LayerNorm->bf16 (blocks 0..2047) + 4 weight
// cast+transposes (blocks 2048..3743). fp32 src[K][N] -> bf16 dst[N][K].
// ---------------------------------------------------------------------------
__global__ __launch_bounds__(256) void prep(
    const float* __restrict__ x, const float* __restrict__ nw,
    const float* __restrict__ nbv, unsigned short* __restrict__ hb,
    const float* __restrict__ w0, unsigned short* __restrict__ t0,
    const float* __restrict__ w1, unsigned short* __restrict__ t1,
    const float* __restrict__ w2, unsigned short* __restrict__ t2,
    const float* __restrict__ w3, unsigned short* __restrict__ t3)
{
    __shared__ unsigned short t[64][68];
    __shared__ float ss[4], sq[4];
    const int tid = threadIdx.x;
    int bid = blockIdx.x;

    if (bid < 2048) {                      // ---- LayerNorm row ----
        const int r = bid;
        const float4 v = ((const float4*)(x + (size_t)r * DM))[tid];
        float s  = v.x + v.y + v.z + v.w;
        float q  = v.x*v.x + v.y*v.y + v.z*v.z + v.w*v.w;
        #pragma unroll
        for (int o = 32; o > 0; o >>= 1) {
            s += __shfl_down(s, o);
            q += __shfl_down(q, o);
        }
        if ((tid & 63) == 0) { ss[tid >> 6] = s; sq[tid >> 6] = q; }
        __syncthreads();
        s = ss[0] + ss[1] + ss[2] + ss[3];
        q = sq[0] + sq[1] + sq[2] + sq[3];
        const float mu  = s * (1.0f / DM);
        const float var = q * (1.0f / DM) - mu * mu;
        const float rs  = rsqrtf(var + 1e-5f);
        const float4 wv = ((const float4*)nw)[tid];
        const float4 bv = ((const float4*)nbv)[tid];
        ushort4 ob;
        ob.x = f2bf((v.x - mu) * rs * wv.x + bv.x);
        ob.y = f2bf((v.y - mu) * rs * wv.y + bv.y);
        ob.z = f2bf((v.z - mu) * rs * wv.z + bv.z);
        ob.w = f2bf((v.w - mu) * rs * wv.w + bv.w);
        *(ushort4*)&hb[(size_t)r * DM + (tid << 2)] = ob;
        return;
    }
    bid -= 2048;                           // ---- transposes ----
    const float* src; unsigned short* dst; int K, N, bx, by;
    if (bid < 1024)      { src = w0; dst = t0; K = 1024; N = 4096;
                           bx = bid & 63; by = bid >> 6; }
    else if (bid < 1120) { int lb = bid - 1024; src = w1; dst = t1;
                           K = 2048; N = 160; bx = lb % 3; by = lb / 3; }
    else if (bid < 1184) { int lb = bid - 1120; src = w2; dst = t2;
                           K = 128; N = 2048; bx = lb & 31; by = lb >> 5; }
    else                 { int lb = bid - 1184; src = w3; dst = t3;
                           K = 2048; N = 1024; bx = lb & 15; by = lb >> 4; }
    const int k0 = by * 64, n0 = bx * 64;
    #pragma unroll
    for (int q = 0; q < 4; ++q) {
        int idx = q * 256 + tid;
        int r = idx >> 4, c = (idx & 15) * 4;
        if (k0 + r < K) {
            #pragma unroll
            for (int e = 0; e < 4; ++e)
                if (n0 + c + e < N)
                    t[r][c + e] = f2bf(src[(size_t)(k0 + r) * N + n0 + c + e]);
        }
    }
    __syncthreads();
    #pragma unroll
    for (int q = 0; q < 4; ++q) {
        int idx = q * 256 + tid;
        int r = idx >> 4, c = (idx & 15) * 4;
        if (n0 + r < N) {
            #pragma unroll
            for (int e = 0; e < 4; ++e)
                if (k0 + c + e < K)
                    dst[(size_t)(n0 + r) * K + k0 + c + e] = t[c + e][r];
        }
    }
}

// ---------------------------------------------------------------------------
// gemm_gl (in_proj): m97 structure — linear LDS [128][64], BK=64,
// global_load_lds width-16 staging, bf16 output.
// C[M,N](bf16) = A[M,K](bf16) @ Bt[N,K](bf16)^T
// ---------------------------------------------------------------------------
__global__ __launch_bounds__(256) void gemm_gl(
    const unsigned short* __restrict__ A,
    const unsigned short* __restrict__ Bt,
    unsigned short* __restrict__ C, int M, int N, int K)
{
    __shared__ unsigned short As[128][64];
    __shared__ unsigned short Bs[128][64];
    const int tid  = threadIdx.x;
    const int m0   = blockIdx.y * 128;
    const int n0   = blockIdx.x * 128;
    const int wave = tid >> 6;
    const int lane = tid & 63;
    const int wr   = (wave >> 1) * 64;
    const int wc   = (wave & 1) * 64;
    const int l15  = lane & 15;
    const int kg   = lane >> 4;          // 0..3
    const int lrow = lane >> 3;          // 0..7  (staging row within 8-row chunk)
    const int lcol = (lane & 7) * 8;     // 0..56 (staging col, 8 bf16 = 16B)

    f32x4 acc[4][4] = {};

    for (int kt = 0; kt < K; kt += 64) {
        __syncthreads();
        #pragma unroll
        for (int q = 0; q < 4; ++q) {
            const int rbase = wave * 32 + q * 8;   // 8 rows = 1 KB per wave-inst
            gload_lds16(&A[(size_t)(m0 + rbase + lrow) * K + kt + lcol],
                        &As[rbase][0]);
            gload_lds16(&Bt[(size_t)(n0 + rbase + lrow) * K + kt + lcol],
                        &Bs[rbase][0]);
        }
        __syncthreads();                           // drains vmcnt before reads
        #pragma unroll
        for (int ks = 0; ks < 2; ++ks) {
            bf16x8 af[4], bfr[4];
            #pragma unroll
            for (int i = 0; i < 4; ++i)
                af[i] = *(const bf16x8*)&As[wr + i * 16 + l15][ks * 32 + kg * 8];
            #pragma unroll
            for (int j = 0; j < 4; ++j)
                bfr[j] = *(const bf16x8*)&Bs[wc + j * 16 + l15][ks * 32 + kg * 8];
            #pragma unroll
            for (int i = 0; i < 4; ++i)
                #pragma unroll
                for (int j = 0; j < 4; ++j)
                    acc[i][j] = __builtin_amdgcn_mfma_f32_16x16x32_bf16(
                        af[i], bfr[j], acc[i][j], 0, 0, 0);
        }
    }
    // C/D layout: col = lane&15, row = (lane>>4)*4 + reg   [m89-verified]
    #pragma unroll
    for (int i = 0; i < 4; ++i) {
        #pragma unroll
        for (int j = 0; j < 4; ++j) {
            const int row = m0 + wr + i * 16 + kg * 4;
            const int col = n0 + wc + j * 16 + l15;
            #pragma unroll
            for (int r = 0; r < 4; ++r)
                C[(size_t)(row + r) * N + col] = f2bf(acc[i][j][r]);
        }
    }
}

// ---------------------------------------------------------------------------
// padded-LDS bf16 MFMA GEMM. 256 thr = 4 waves (2x2).
// EPI: 0 fp32 out, 1 softplus(acc+bias[col]) fp32, 2 +resid fp32,
//      3 bf16 out.
// Tile note (round-9 lesson): keep BN >= 64 for long-K GEMMs.
// ---------------------------------------------------------------------------
template<int BM, int BN, int EPI>
__global__ __launch_bounds__(256) void gemm_bf16(
    const unsigned short* __restrict__ A,
    const unsigned short* __restrict__ Bt,
    float* __restrict__ C, int M, int N, int K, int kpb,
    const float* __restrict__ bias,
    const float* __restrict__ resid)
{
    constexpr int LDT = 72;
    __shared__ unsigned short As[BM][LDT];
    __shared__ unsigned short Bs[BN][LDT];
    const int tid  = threadIdx.x;
    const int m0   = blockIdx.y * BM;
    const int n0   = blockIdx.x * BN;
    const int kbeg = blockIdx.z * kpb;
    const int kend = kbeg + kpb;
    float* Cw = C + (size_t)blockIdx.z * M * N;
    const int wave = tid >> 6;
    const int lane = tid & 63;
    const int wr   = (wave >> 1) * (BM / 2);
    const int wc   = (wave & 1) * (BN / 2);
    constexpr int FM = BM / 32;
    constexpr int FN = BN / 32;
    const int l15 = lane & 15;
    const int kg  = lane >> 4;

    f32x4 acc[FM][FN] = {};

    for (int kt = kbeg; kt < kend; kt += 64) {
        __syncthreads();
        #pragma unroll
        for (int q = 0; q < BM / 32; ++q) {
            int idx = q * 256 + tid;
            int r = idx >> 3, c = (idx & 7) * 8;
            *(uint4*)&As[r][c] = *(const uint4*)&A[(size_t)(m0 + r) * K + kt + c];
        }
        #pragma unroll
        for (int q = 0; q < BN / 32; ++q) {
            int idx = q * 256 + tid;
            int r = idx >> 3, c = (idx & 7) * 8;
            *(uint4*)&Bs[r][c] = *(const uint4*)&Bt[(size_t)(n0 + r) * K + kt + c];
        }
        __syncthreads();
        #pragma unroll
        for (int ks = 0; ks < 2; ++ks) {
            bf16x8 af[FM], bfr[FN];
            #pragma unroll
            for (int i = 0; i < FM; ++i)
                af[i] = *(const bf16x8*)&As[wr + i * 16 + l15][ks * 32 + kg * 8];
            #pragma unroll
            for (int j = 0; j < FN; ++j)
                bfr[j] = *(const bf16x8*)&Bs[wc + j * 16 + l15][ks * 32 + kg * 8];
            #pragma unroll
            for (int i = 0; i < FM; ++i)
                #pragma unroll
                for (int j = 0; j < FN; ++j)
                    acc[i][j] = __builtin_amdgcn_mfma_f32_16x16x32_bf16(
                        af[i], bfr[j], acc[i][j], 0, 0, 0);
        }
    }
    // C/D layout: col = lane&15, row = (lane>>4)*4 + reg   [m89-verified]
    #pragma unroll
    for (int i = 0; i < FM; ++i) {
        #pragma unroll
        for (int j = 0; j < FN; ++j) {
            const int row = m0 + wr + i * 16 + kg * 4;
            const int col = n0 + wc + j * 16 + l15;
            #pragma unroll
            for (int r = 0; r < 4; ++r) {
                float v = acc[i][j][r];
                if (EPI == 1) {
                    float t = v + bias[col];
                    v = (t > 20.f) ? t : log1pf(__expf(t));
                } else if (EPI == 2) {
                    v += resid[(size_t)(row + r) * N + col];
                }
                if (EPI == 3)
                    ((unsigned short*)Cw)[(size_t)(row + r) * N + col] = f2bf(v);
                else
                    Cw[(size_t)(row + r) * N + col] = v;
            }
        }
    }
}

// ---------------------------------------------------------------------------
// x_proj split-K reduce: sum 4 partials; write xp fp32 + dr bf16 (cols<128)
// ---------------------------------------------------------------------------
__global__ __launch_bounds__(256) void xproj_reduce(
    const float* __restrict__ P4, float* __restrict__ xp,
    unsigned short* __restrict__ drb)
{
    const int idx = blockIdx.x * 256 + threadIdx.x;   // < 2048*160
    float s = 0.f;
    #pragma unroll
    for (int j = 0; j < 4; ++j)
        s += P4[(size_t)j * (MROWS * NXP) + idx];
    xp[idx] = s;
    const int row = idx / NXP, col = idx - row * NXP;
    if (col < DTR) drb[(size_t)row * DTR + col] = f2bf(s);
}

// ---------------------------------------------------------------------------
// causal depthwise conv (K=4) + SiLU over bf16 xr; writes xsb bf16, gb bf16
// ---------------------------------------------------------------------------
__global__ __launch_bounds__(256) void conv_silu(
    const unsigned short* __restrict__ xrb, const float* __restrict__ cw,
    const float* __restrict__ cb, unsigned short* __restrict__ xsb,
    unsigned short* __restrict__ gb)
{
    const int idx = blockIdx.x * 256 + threadIdx.x;
    const int d = idx & (DI - 1);
    const int t = (idx >> 11) & (LLEN - 1);
    const int b = idx >> 21;
    const float4 wv = ((const float4*)cw)[d];
    const float w[4] = {wv.x, wv.y, wv.z, wv.w};
    float acc = cb[d];
    #pragma unroll
    for (int k = 0; k < 4; ++k) {
        const int tt = t + k - 3;
        if (tt >= 0)
            acc = fmaf(w[k], bf2f(xrb[((size_t)(b * LLEN + tt) << 12) + d]), acc);
    }
    const float sig = 1.f / (1.f + __expf(-acc));
    const float v = acc * sig;
    xsb[idx] = f2bf(v);
    const float r = bf2f(xrb[((size_t)(b * LLEN + t) << 12) + DI + d]);
    gb[idx] = f2bf(r / (1.f + __expf(-r)));
}

// ---------------------------------------------------------------------------
// Scan pass A: 4 threads per channel (4 states each). Walks chunk with h0=0.
// dio <- y'_t (in-place over delta); cd <- cumDelta_t; u read from bf16 xsb.
// S = chunk-final h.
// ---------------------------------------------------------------------------
__global__ __launch_bounds__(256) void scan_part(
    float* __restrict__ dio, const unsigned short* __restrict__ ub,
    float* __restrict__ cd, const float* __restrict__ xp,
    const float* __restrict__ A_log, const float* __restrict__ Dp,
    float* __restrict__ S)
{
    const int blk  = blockIdx.x;               // BSZ*NCH*32 = 2048
    const int dgrp = blk & 31;                 // 32 groups of 64 channels
    const int j    = (blk >> 5) & (NCH - 1);
    const int b    = blk >> 10;
    const int c    = threadIdx.x >> 2;         // local channel 0..63
    const int sg   = threadIdx.x & 3;          // state group
    const int d    = dgrp * 64 + c;
    const int nb   = sg * 4;
    float aL[4], h[4];
    #pragma unroll
    for (int n = 0; n < 4; ++n) {
        aL[n] = -__expf(A_log[d * DS + nb + n]) * 1.44269504088896f;
        h[n] = 0.f;
    }
    const float Dd = Dp[d];
    float sd = 0.f;
    const int t0 = j * CHL;
    for (int t = t0; t < t0 + CHL; ++t) {
        const size_t row = (size_t)(b * LLEN + t);
        const float dlt = dio[row * DI + d];
        const float u   = bf2f(ub[row * DI + d]);
        const float du  = dlt * u;
        sd += dlt;
        const float* Bp = &xp[row * NXP + DTR + nb];
        const float* Cp = &xp[row * NXP + DTR + DS + nb];
        float y = sg ? 0.f : Dd * u;
        #pragma unroll
        for (int n = 0; n < 4; ++n) {
            const float dA = exp2f(dlt * aL[n]);
            h[n] = fmaf(dA, h[n], du * Bp[n]);
            y = fmaf(h[n], Cp[n], y);
        }
        y += __shfl_xor(y, 1);
        y += __shfl_xor(y, 2);
        if (!sg) {
            dio[row * DI + d] = y;             // y' (partial, h0=0)
            cd[row * DI + d]  = sd;            // inclusive cumulative delta
        }
    }
    float* So = &S[(((size_t)j * BSZ + b) * DI + d) * DS + nb];
    #pragma unroll
    for (int n = 0; n < 4; ++n) So[n] = h[n];
}

// ---------------------------------------------------------------------------
// Scan pass B: inter-chunk fix-up, thread per (b,d,n).
// ---------------------------------------------------------------------------
__global__ __launch_bounds__(256) void scan_fix(
    float* __restrict__ S, const float* __restrict__ cumD,
    const float* __restrict__ A_log)
{
    const int c = blockIdx.x * 256 + threadIdx.x;   // < 2*2048*16
    const int n = c & 15;
    const int d = (c >> 4) & (DI - 1);
    const int b = c >> 15;
    const float aL = -__expf(A_log[d * DS + n]) * 1.44269504088896f;
    float h = 0.f;
    #pragma unroll
    for (int j = 0; j < NCH; ++j) {
        const float sd = cumD[(size_t)(b * LLEN + j * CHL + CHL - 1) * DI + d];
        const size_t base = (((size_t)j * BSZ + b) * DI + d) * DS + n;
        const float Pj = exp2f(aL * sd);
        const float Sj = S[base];
        S[base] = h;
        h = fmaf(Pj, h, Sj);
    }
}

// ---------------------------------------------------------------------------
// Scan pass C (correction, no recurrence): 4 threads per channel.
//   y_t = y'_t + sum_n C_t[n]*exp2(aL[n]*cumD_t)*H0[n];  yb = bf16(y*g)
// ---------------------------------------------------------------------------
__global__ __launch_bounds__(256) void scan_corr(
    const float* __restrict__ yp, const float* __restrict__ cumD,
    const float* __restrict__ xp, const unsigned short* __restrict__ gb,
    const float* __restrict__ A_log, const float* __restrict__ H0,
    unsigned short* __restrict__ yb)
{
    const int blk  = blockIdx.x;               // 2048
    const int dgrp = blk & 31;
    const int j    = (blk >> 5) & (NCH - 1);
    const int b    = blk >> 10;
    const int c    = threadIdx.x >> 2;
    const int sg   = threadIdx.x & 3;
    const int d    = dgrp * 64 + c;
    const int nb   = sg * 4;
    float aL[4], H[4];
    const float* Hp = &H0[(((size_t)j * BSZ + b) * DI + d) * DS + nb];
    #pragma unroll
    for (int n = 0; n < 4; ++n) {
        aL[n] = -__expf(A_log[d * DS + nb + n]) * 1.44269504088896f;
        H[n] = Hp[n];
    }
    const int t0 = j * CHL;
    for (int t = t0; t < t0 + CHL; ++t) {
        const size_t row = (size_t)(b * LLEN + t);
        const float cdv = cumD[row * DI + d];
        const float* Cp = &xp[row * NXP + DTR + DS + nb];
        float corr = 0.f;
        #pragma unroll
        for (int n = 0; n < 4; ++n)
            corr = fmaf(H[n] * exp2f(aL[n] * cdv), Cp[n], corr);
        corr += __shfl_xor(corr, 1);
        corr += __shfl_xor(corr, 2);
        if (!sg) {
            const float y = yp[row * DI + d] + corr;
            yb[row * DI + d] = f2bf(y * bf2f(gb[row * DI + d]));
        }
    }
}

// ---------------------------------------------------------------------------
extern "C" void kernel_launch(void* const* d_in, const int* in_sizes, int n_in,
                              void* d_out, int out_size, void* d_ws, size_t ws_size,
                              hipStream_t stream)
{
    (void)in_sizes; (void)n_in; (void)out_size; (void)ws_size;
    const float* x         = (const float*)d_in[0];
    const float* norm_w    = (const float*)d_in[1];
    const float* norm_b    = (const float*)d_in[2];
    const float* in_proj_w = (const float*)d_in[3];   // (1024, 4096)
    const float* conv_w    = (const float*)d_in[4];
    const float* conv_b    = (const float*)d_in[5];
    const float* x_proj_w  = (const float*)d_in[6];   // (2048, 160)
    const float* dt_proj_w = (const float*)d_in[7];   // (128, 2048)
    const float* dt_proj_b = (const float*)d_in[8];
    const float* A_log     = (const float*)d_in[9];
    const float* D_param   = (const float*)d_in[10];
    const float* out_proj_w= (const float*)d_in[11];  // (2048, 1024)
    float* out = (float*)d_out;

    // Workspace overlays (identical to round-11 proven layout):
    char* ws = (char*)d_ws;
    unsigned short* xrb   = (unsigned short*)(ws);             // 16M  d2..d3
    float*          P4    = (float*)(ws);                      // 5.25M d4..d5
    float*          delta = (float*)(ws);                      // 16M  d6..d9
    float*          Sbuf  = (float*)(ws + 16777216);           // 8M   d7..d9
    float*          xp    = (float*)(ws + 25165824);           // 1.25M d5..d9
    unsigned short* drb   = (unsigned short*)(ws + 27262976);  // 512K d5..d6
    float*          cd    = (float*)(ws + 33554432);           // 16M  d7..d9
    unsigned short* gb    = (unsigned short*)(ws + 50331648);  // 8M   d3..d9
    unsigned short* wInT  = (unsigned short*)(ws + 50331648);  // 8M   d1..d2
    unsigned short* hb    = (unsigned short*)(ws + 58720256);  // 4M   d1..d2
    unsigned short* wOutT = (unsigned short*)(ws + 62914560);  // 4M   d1..d10
    unsigned short* xsb   = (unsigned short*)(ws + 67108864);  // 8M   d3..d7
    unsigned short* yb    = (unsigned short*)(ws + 67108864);  // 8M   d9..d10
    unsigned short* wXT   = (unsigned short*)(ws + 75497472);  // 640K d1..d4
    unsigned short* dtwT  = (unsigned short*)(ws + 76152832);  // 512K d1..d6

    // d1. LN + all four weight transposes, one dispatch
    prep<<<3744, 256, 0, stream>>>(x, norm_w, norm_b, hb,
                                   in_proj_w, wInT, x_proj_w, wXT,
                                   dt_proj_w, dtwT, out_proj_w, wOutT);

    // d2. in_proj -> xrb bf16  [ISOLATED CHANGE: m97-style global_load_lds
    // kernel — round-5/6 arithmetic suggests this was faster; clean A/B now]
    gemm_gl<<<dim3(32, 16), 256, 0, stream>>>(
        hb, wInT, xrb, MROWS, 2 * DI, DM);

    // d3. conv + silu over bf16 xr -> xsb bf16, gb bf16
    conv_silu<<<(BSZ * LLEN * DI) / 256, 256, 0, stream>>>(
        xrb, conv_w, conv_b, xsb, gb);

    // d4. x_proj MFMA split-K=4 -> P4 partials  [320 blocks, 8 K-steps each]
    gemm_bf16<128, 32, 0><<<dim3(5, 16, 4), 256, 0, stream>>>(
        xsb, wXT, P4, MROWS, NXP, DI, DI / 4, nullptr, nullptr);
    // d5. reduce -> xp fp32, drb bf16
    xproj_reduce<<<(MROWS * NXP) / 256, 256, 0, stream>>>(P4, xp, drb);

    // d6. dt_proj MFMA + softplus -> delta  [BN=64, K=128: 2 K-steps]
    gemm_bf16<128, 64, 1><<<dim3(32, 16, 1), 256, 0, stream>>>(
        drb, dtwT, delta, MROWS, DI, DTR, DTR, dt_proj_b, nullptr);

    // d7-d9. chunked selective scan (u from bf16 xsb; cumD in own fp32 slot)
    scan_part<<<BSZ * NCH * (DI / 64), 256, 0, stream>>>(
        delta, xsb, cd, xp, A_log, D_param, Sbuf);
    scan_fix<<<(BSZ * DI * DS) / 256, 256, 0, stream>>>(Sbuf, cd, A_log);
    scan_corr<<<BSZ * NCH * (DI / 64), 256, 0, stream>>>(
        delta, cd, xp, gb, A_log, Sbuf, yb);

    // d10. out_proj MFMA + residual -> out  [BN=64, 256 blocks — proven]
    gemm_bf16<128, 64, 2><<<dim3(16, 16, 1), 256, 0, stream>>>(
        yb, wOutT, out, MROWS, DM, DI, DI, nullptr, x);
}

// Round 13
// 200.863 us; speedup vs baseline: 1.0054x; 1.0054x over previous
//
#include <hip/hip_runtime.h>
#include <hip/hip_bf16.h>
#include <math.h>

// Problem constants
#define BSZ     2
#define LLEN    1024
#define DM      1024
#define DI      2048
#define DS      16
#define DTR     128
#define NXP     160          // DTR + 2*DS
#define MROWS   (BSZ*LLEN)   // 2048
#define NCH     32           // scan chunks
#define CHL     (LLEN/NCH)   // 32 steps per chunk

typedef short  bf16x8 __attribute__((ext_vector_type(8)));   // 8 bf16 (4 VGPRs)
typedef float  f32x4  __attribute__((ext_vector_type(4)));

__device__ __forceinline__ unsigned short f2bf(float f) {
    unsigned int u = __float_as_uint(f);
    return (unsigned short)((u + 0x7FFFu + ((u >> 16) & 1u)) >> 16);   // RNE
}
__device__ __forceinline__ float bf2f(unsigned short u) {
    return __uint_as_float((unsigned int)u << 16);
}

// ---------------------------------------------------------------------------
// prep: ONE dispatch = LayerNorm->bf16 (blocks 0..2047) + 4 weight
// cast+transposes (blocks 2048..3743). fp32 src[K][N] -> bf16 dst[N][K].
// ---------------------------------------------------------------------------
__global__ __launch_bounds__(256) void prep(
    const float* __restrict__ x, const float* __restrict__ nw,
    const float* __restrict__ nbv, unsigned short* __restrict__ hb,
    const float* __restrict__ w0, unsigned short* __restrict__ t0,
    const float* __restrict__ w1, unsigned short* __restrict__ t1,
    const float* __restrict__ w2, unsigned short* __restrict__ t2,
    const float* __restrict__ w3, unsigned short* __restrict__ t3)
{
    __shared__ unsigned short t[64][68];
    __shared__ float ss[4], sq[4];
    const int tid = threadIdx.x;
    int bid = blockIdx.x;

    if (bid < 2048) {                      // ---- LayerNorm row ----
        const int r = bid;
        const float4 v = ((const float4*)(x + (size_t)r * DM))[tid];
        float s  = v.x + v.y + v.z + v.w;
        float q  = v.x*v.x + v.y*v.y + v.z*v.z + v.w*v.w;
        #pragma unroll
        for (int o = 32; o > 0; o >>= 1) {
            s += __shfl_down(s, o);
            q += __shfl_down(q, o);
        }
        if ((tid & 63) == 0) { ss[tid >> 6] = s; sq[tid >> 6] = q; }
        __syncthreads();
        s = ss[0] + ss[1] + ss[2] + ss[3];
        q = sq[0] + sq[1] + sq[2] + sq[3];
        const float mu  = s * (1.0f / DM);
        const float var = q * (1.0f / DM) - mu * mu;
        const float rs  = rsqrtf(var + 1e-5f);
        const float4 wv = ((const float4*)nw)[tid];
        const float4 bv = ((const float4*)nbv)[tid];
        ushort4 ob;
        ob.x = f2bf((v.x - mu) * rs * wv.x + bv.x);
        ob.y = f2bf((v.y - mu) * rs * wv.y + bv.y);
        ob.z = f2bf((v.z - mu) * rs * wv.z + bv.z);
        ob.w = f2bf((v.w - mu) * rs * wv.w + bv.w);
        *(ushort4*)&hb[(size_t)r * DM + (tid << 2)] = ob;
        return;
    }
    bid -= 2048;                           // ---- transposes ----
    const float* src; unsigned short* dst; int K, N, bx, by;
    if (bid < 1024)      { src = w0; dst = t0; K = 1024; N = 4096;
                           bx = bid & 63; by = bid >> 6; }
    else if (bid < 1120) { int lb = bid - 1024; src = w1; dst = t1;
                           K = 2048; N = 160; bx = lb % 3; by = lb / 3; }
    else if (bid < 1184) { int lb = bid - 1120; src = w2; dst = t2;
                           K = 128; N = 2048; bx = lb & 31; by = lb >> 5; }
    else                 { int lb = bid - 1184; src = w3; dst = t3;
                           K = 2048; N = 1024; bx = lb & 15; by = lb >> 4; }
    const int k0 = by * 64, n0 = bx * 64;
    #pragma unroll
    for (int q = 0; q < 4; ++q) {
        int idx = q * 256 + tid;
        int r = idx >> 4, c = (idx & 15) * 4;
        if (k0 + r < K) {
            #pragma unroll
            for (int e = 0; e < 4; ++e)
                if (n0 + c + e < N)
                    t[r][c + e] = f2bf(src[(size_t)(k0 + r) * N + n0 + c + e]);
        }
    }
    __syncthreads();
    #pragma unroll
    for (int q = 0; q < 4; ++q) {
        int idx = q * 256 + tid;
        int r = idx >> 4, c = (idx & 15) * 4;
        if (n0 + r < N) {
            #pragma unroll
            for (int e = 0; e < 4; ++e)
                if (k0 + c + e < K)
                    dst[(size_t)(n0 + r) * K + k0 + c + e] = t[c + e][r];
        }
    }
}

// ---------------------------------------------------------------------------
// padded-LDS bf16 MFMA GEMM. 256 thr = 4 waves (2x2).
// EPI: 0 fp32 out, 1 softplus(acc+bias) fp32, 2 +resid fp32,
//      3 bf16 out, 4 softplus(acc+bias) bf16 out.
// Tile note (round-9 lesson): keep BN >= 64 for long-K GEMMs.
// Staging note (round-12 A/B): padded reg-staging == global_load_lds at
// K<=1024-scale shapes; padded kept for its conflict-free reads.
// ---------------------------------------------------------------------------
template<int BM, int BN, int EPI>
__global__ __launch_bounds__(256) void gemm_bf16(
    const unsigned short* __restrict__ A,
    const unsigned short* __restrict__ Bt,
    float* __restrict__ C, int M, int N, int K, int kpb,
    const float* __restrict__ bias,
    const float* __restrict__ resid)
{
    constexpr int LDT = 72;
    __shared__ unsigned short As[BM][LDT];
    __shared__ unsigned short Bs[BN][LDT];
    const int tid  = threadIdx.x;
    const int m0   = blockIdx.y * BM;
    const int n0   = blockIdx.x * BN;
    const int kbeg = blockIdx.z * kpb;
    const int kend = kbeg + kpb;
    float* Cw = C + (size_t)blockIdx.z * M * N;
    const int wave = tid >> 6;
    const int lane = tid & 63;
    const int wr   = (wave >> 1) * (BM / 2);
    const int wc   = (wave & 1) * (BN / 2);
    constexpr int FM = BM / 32;
    constexpr int FN = BN / 32;
    const int l15 = lane & 15;
    const int kg  = lane >> 4;

    f32x4 acc[FM][FN] = {};

    for (int kt = kbeg; kt < kend; kt += 64) {
        __syncthreads();
        #pragma unroll
        for (int q = 0; q < BM / 32; ++q) {
            int idx = q * 256 + tid;
            int r = idx >> 3, c = (idx & 7) * 8;
            *(uint4*)&As[r][c] = *(const uint4*)&A[(size_t)(m0 + r) * K + kt + c];
        }
        #pragma unroll
        for (int q = 0; q < BN / 32; ++q) {
            int idx = q * 256 + tid;
            int r = idx >> 3, c = (idx & 7) * 8;
            *(uint4*)&Bs[r][c] = *(const uint4*)&Bt[(size_t)(n0 + r) * K + kt + c];
        }
        __syncthreads();
        #pragma unroll
        for (int ks = 0; ks < 2; ++ks) {
            bf16x8 af[FM], bfr[FN];
            #pragma unroll
            for (int i = 0; i < FM; ++i)
                af[i] = *(const bf16x8*)&As[wr + i * 16 + l15][ks * 32 + kg * 8];
            #pragma unroll
            for (int j = 0; j < FN; ++j)
                bfr[j] = *(const bf16x8*)&Bs[wc + j * 16 + l15][ks * 32 + kg * 8];
            #pragma unroll
            for (int i = 0; i < FM; ++i)
                #pragma unroll
                for (int j = 0; j < FN; ++j)
                    acc[i][j] = __builtin_amdgcn_mfma_f32_16x16x32_bf16(
                        af[i], bfr[j], acc[i][j], 0, 0, 0);
        }
    }
    // C/D layout: col = lane&15, row = (lane>>4)*4 + reg   [m89-verified]
    #pragma unroll
    for (int i = 0; i < FM; ++i) {
        #pragma unroll
        for (int j = 0; j < FN; ++j) {
            const int row = m0 + wr + i * 16 + kg * 4;
            const int col = n0 + wc + j * 16 + l15;
            #pragma unroll
            for (int r = 0; r < 4; ++r) {
                float v = acc[i][j][r];
                if (EPI == 1 || EPI == 4) {
                    float t = v + bias[col];
                    v = (t > 20.f) ? t : log1pf(__expf(t));
                } else if (EPI == 2) {
                    v += resid[(size_t)(row + r) * N + col];
                }
                if (EPI == 3 || EPI == 4)
                    ((unsigned short*)Cw)[(size_t)(row + r) * N + col] = f2bf(v);
                else
                    Cw[(size_t)(row + r) * N + col] = v;
            }
        }
    }
}

// ---------------------------------------------------------------------------
// x_proj split-K reduce: sum 4 partials; write xp fp32 + dr bf16 (cols<128)
// ---------------------------------------------------------------------------
__global__ __launch_bounds__(256) void xproj_reduce(
    const float* __restrict__ P4, float* __restrict__ xp,
    unsigned short* __restrict__ drb)
{
    const int idx = blockIdx.x * 256 + threadIdx.x;   // < 2048*160
    float s = 0.f;
    #pragma unroll
    for (int j = 0; j < 4; ++j)
        s += P4[(size_t)j * (MROWS * NXP) + idx];
    xp[idx] = s;
    const int row = idx / NXP, col = idx - row * NXP;
    if (col < DTR) drb[(size_t)row * DTR + col] = f2bf(s);
}

// ---------------------------------------------------------------------------
// causal depthwise conv (K=4) + SiLU over bf16 xr; writes xsb bf16, gb bf16
// ---------------------------------------------------------------------------
__global__ __launch_bounds__(256) void conv_silu(
    const unsigned short* __restrict__ xrb, const float* __restrict__ cw,
    const float* __restrict__ cb, unsigned short* __restrict__ xsb,
    unsigned short* __restrict__ gb)
{
    const int idx = blockIdx.x * 256 + threadIdx.x;
    const int d = idx & (DI - 1);
    const int t = (idx >> 11) & (LLEN - 1);
    const int b = idx >> 21;
    const float4 wv = ((const float4*)cw)[d];
    const float w[4] = {wv.x, wv.y, wv.z, wv.w};
    float acc = cb[d];
    #pragma unroll
    for (int k = 0; k < 4; ++k) {
        const int tt = t + k - 3;
        if (tt >= 0)
            acc = fmaf(w[k], bf2f(xrb[((size_t)(b * LLEN + tt) << 12) + d]), acc);
    }
    const float sig = 1.f / (1.f + __expf(-acc));
    const float v = acc * sig;
    xsb[idx] = f2bf(v);
    const float r = bf2f(xrb[((size_t)(b * LLEN + t) << 12) + DI + d]);
    gb[idx] = f2bf(r / (1.f + __expf(-r)));
}

// ---------------------------------------------------------------------------
// Scan pass A: 4 threads per channel (4 states each). Walks chunk with h0=0.
// ALL bf16 I/O: dio (bf16 delta in / y' out, in-place), cd bf16 cumDelta,
// u from bf16 xsb. S (fp32) = chunk-final h.
// ---------------------------------------------------------------------------
__global__ __launch_bounds__(256) void scan_part(
    unsigned short* __restrict__ dio, const unsigned short* __restrict__ ub,
    unsigned short* __restrict__ cd, const float* __restrict__ xp,
    const float* __restrict__ A_log, const float* __restrict__ Dp,
    float* __restrict__ S)
{
    const int blk  = blockIdx.x;               // BSZ*NCH*32 = 2048
    const int dgrp = blk & 31;                 // 32 groups of 64 channels
    const int j    = (blk >> 5) & (NCH - 1);
    const int b    = blk >> 10;
    const int c    = threadIdx.x >> 2;         // local channel 0..63
    const int sg   = threadIdx.x & 3;          // state group
    const int d    = dgrp * 64 + c;
    const int nb   = sg * 4;
    float aL[4], h[4];
    #pragma unroll
    for (int n = 0; n < 4; ++n) {
        aL[n] = -__expf(A_log[d * DS + nb + n]) * 1.44269504088896f;
        h[n] = 0.f;
    }
    const float Dd = Dp[d];
    float sd = 0.f;
    const int t0 = j * CHL;
    for (int t = t0; t < t0 + CHL; ++t) {
        const size_t row = (size_t)(b * LLEN + t);
        const float dlt = bf2f(dio[row * DI + d]);
        const float u   = bf2f(ub[row * DI + d]);
        const float du  = dlt * u;
        sd += dlt;
        const float* Bp = &xp[row * NXP + DTR + nb];
        const float* Cp = &xp[row * NXP + DTR + DS + nb];
        float y = sg ? 0.f : Dd * u;
        #pragma unroll
        for (int n = 0; n < 4; ++n) {
            const float dA = exp2f(dlt * aL[n]);
            h[n] = fmaf(dA, h[n], du * Bp[n]);
            y = fmaf(h[n], Cp[n], y);
        }
        y += __shfl_xor(y, 1);
        y += __shfl_xor(y, 2);
        if (!sg) {
            dio[row * DI + d] = f2bf(y);       // y' (partial, h0=0)
            cd[row * DI + d]  = f2bf(sd);      // inclusive cumulative delta
        }
    }
    float* So = &S[(((size_t)j * BSZ + b) * DI + d) * DS + nb];
    #pragma unroll
    for (int n = 0; n < 4; ++n) So[n] = h[n];
}

// ---------------------------------------------------------------------------
// Scan pass B: inter-chunk fix-up, thread per (b,d,n). cd bf16.
// ---------------------------------------------------------------------------
__global__ __launch_bounds__(256) void scan_fix(
    float* __restrict__ S, const unsigned short* __restrict__ cumD,
    const float* __restrict__ A_log)
{
    const int c = blockIdx.x * 256 + threadIdx.x;   // < 2*2048*16
    const int n = c & 15;
    const int d = (c >> 4) & (DI - 1);
    const int b = c >> 15;
    const float aL = -__expf(A_log[d * DS + n]) * 1.44269504088896f;
    float h = 0.f;
    #pragma unroll
    for (int j = 0; j < NCH; ++j) {
        const float sd = bf2f(cumD[(size_t)(b * LLEN + j * CHL + CHL - 1) * DI + d]);
        const size_t base = (((size_t)j * BSZ + b) * DI + d) * DS + n;
        const float Pj = exp2f(aL * sd);
        const float Sj = S[base];
        S[base] = h;
        h = fmaf(Pj, h, Sj);
    }
}

// ---------------------------------------------------------------------------
// Scan pass C (correction, no recurrence): 4 threads per channel. bf16 I/O.
//   y_t = y'_t + sum_n C_t[n]*exp2(aL[n]*cumD_t)*H0[n];  yb = bf16(y*g)
// ---------------------------------------------------------------------------
__global__ __launch_bounds__(256) void scan_corr(
    const unsigned short* __restrict__ yp, const unsigned short* __restrict__ cumD,
    const float* __restrict__ xp, const unsigned short* __restrict__ gb,
    const float* __restrict__ A_log, const float* __restrict__ H0,
    unsigned short* __restrict__ yb)
{
    const int blk  = blockIdx.x;               // 2048
    const int dgrp = blk & 31;
    const int j    = (blk >> 5) & (NCH - 1);
    const int b    = blk >> 10;
    const int c    = threadIdx.x >> 2;
    const int sg   = threadIdx.x & 3;
    const int d    = dgrp * 64 + c;
    const int nb   = sg * 4;
    float aL[4], H[4];
    const float* Hp = &H0[(((size_t)j * BSZ + b) * DI + d) * DS + nb];
    #pragma unroll
    for (int n = 0; n < 4; ++n) {
        aL[n] = -__expf(A_log[d * DS + nb + n]) * 1.44269504088896f;
        H[n] = Hp[n];
    }
    const int t0 = j * CHL;
    for (int t = t0; t < t0 + CHL; ++t) {
        const size_t row = (size_t)(b * LLEN + t);
        const float cdv = bf2f(cumD[row * DI + d]);
        const float* Cp = &xp[row * NXP + DTR + DS + nb];
        float corr = 0.f;
        #pragma unroll
        for (int n = 0; n < 4; ++n)
            corr = fmaf(H[n] * exp2f(aL[n] * cdv), Cp[n], corr);
        corr += __shfl_xor(corr, 1);
        corr += __shfl_xor(corr, 2);
        if (!sg) {
            const float y = bf2f(yp[row * DI + d]) + corr;
            yb[row * DI + d] = f2bf(y * bf2f(gb[row * DI + d]));
        }
    }
}

// ---------------------------------------------------------------------------
extern "C" void kernel_launch(void* const* d_in, const int* in_sizes, int n_in,
                              void* d_out, int out_size, void* d_ws, size_t ws_size,
                              hipStream_t stream)
{
    (void)in_sizes; (void)n_in; (void)out_size; (void)ws_size;
    const float* x         = (const float*)d_in[0];
    const float* norm_w    = (const float*)d_in[1];
    const float* norm_b    = (const float*)d_in[2];
    const float* in_proj_w = (const float*)d_in[3];   // (1024, 4096)
    const float* conv_w    = (const float*)d_in[4];
    const float* conv_b    = (const float*)d_in[5];
    const float* x_proj_w  = (const float*)d_in[6];   // (2048, 160)
    const float* dt_proj_w = (const float*)d_in[7];   // (128, 2048)
    const float* dt_proj_b = (const float*)d_in[8];
    const float* A_log     = (const float*)d_in[9];
    const float* D_param   = (const float*)d_in[10];
    const float* out_proj_w= (const float*)d_in[11];  // (2048, 1024)
    float* out = (float*)d_out;

    // Workspace overlays (per-dispatch liveness audited):
    //   d1 prep:      writes hb, wInT, wXT, dtwT, wOutT
    //   d2 in_proj:   hb,wInT -> xrb bf16 (0..16M)
    //   d3 conv:      xrb -> xsb(67.1M), gb(50.3M; wInT dead)
    //   d4 x_proj:    xsb,wXT -> P4(0..5.25M; xrb dead)
    //   d5 reduce:    P4 -> xp(25.2M), drb(27.3M)
    //   d6 dt_proj:   drb,dtwT -> deltab bf16 (0..8M)
    //   d7 scan_part: deltab(in-place y'), xsb, xp -> cdb(33.5M), Sbuf(16.8M)
    //   d8 scan_fix:  Sbuf, cdb
    //   d9 scan_corr: deltab,cdb,xp,gb,Sbuf -> yb(67.1M over dead xsb)
    //   d10 out_proj: yb,wOutT(62.9M),x -> out
    char* ws = (char*)d_ws;
    unsigned short* xrb    = (unsigned short*)(ws);             // 16M  d2..d3
    float*          P4     = (float*)(ws);                      // 5.25M d4..d5
    unsigned short* deltab = (unsigned short*)(ws);             // 8M   d6..d9
    float*          Sbuf   = (float*)(ws + 16777216);           // 8M   d7..d9
    float*          xp     = (float*)(ws + 25165824);           // 1.25M d5..d9
    unsigned short* drb    = (unsigned short*)(ws + 27262976);  // 512K d5..d6
    unsigned short* cdb    = (unsigned short*)(ws + 33554432);  // 8M   d7..d9
    unsigned short* gb     = (unsigned short*)(ws + 50331648);  // 8M   d3..d9
    unsigned short* wInT   = (unsigned short*)(ws + 50331648);  // 8M   d1..d2
    unsigned short* hb     = (unsigned short*)(ws + 58720256);  // 4M   d1..d2
    unsigned short* wOutT  = (unsigned short*)(ws + 62914560);  // 4M   d1..d10
    unsigned short* xsb    = (unsigned short*)(ws + 67108864);  // 8M   d3..d7
    unsigned short* yb     = (unsigned short*)(ws + 67108864);  // 8M   d9..d10
    unsigned short* wXT    = (unsigned short*)(ws + 75497472);  // 640K d1..d4
    unsigned short* dtwT   = (unsigned short*)(ws + 76152832);  // 512K d1..d6

    // d1. LN + all four weight transposes, one dispatch
    prep<<<3744, 256, 0, stream>>>(x, norm_w, norm_b, hb,
                                   in_proj_w, wInT, x_proj_w, wXT,
                                   dt_proj_w, dtwT, out_proj_w, wOutT);

    // d2. in_proj -> xrb bf16  [padded kernel — locked after r12 A/B]
    gemm_bf16<128, 128, 3><<<dim3(32, 16, 1), 256, 0, stream>>>(
        hb, wInT, (float*)xrb, MROWS, 2 * DI, DM, DM, nullptr, nullptr);

    // d3. conv + silu over bf16 xr -> xsb bf16, gb bf16
    conv_silu<<<(BSZ * LLEN * DI) / 256, 256, 0, stream>>>(
        xrb, conv_w, conv_b, xsb, gb);

    // d4. x_proj MFMA split-K=4 -> P4 partials  [320 blocks, 8 K-steps each]
    gemm_bf16<128, 32, 0><<<dim3(5, 16, 4), 256, 0, stream>>>(
        xsb, wXT, P4, MROWS, NXP, DI, DI / 4, nullptr, nullptr);
    // d5. reduce -> xp fp32, drb bf16
    xproj_reduce<<<(MROWS * NXP) / 256, 256, 0, stream>>>(P4, xp, drb);

    // d6. dt_proj MFMA + softplus -> deltab bf16  [EPI=4 halves write]
    gemm_bf16<128, 64, 4><<<dim3(32, 16, 1), 256, 0, stream>>>(
        drb, dtwT, (float*)deltab, MROWS, DI, DTR, DTR, dt_proj_b, nullptr);

    // d7-d9. chunked selective scan (all-bf16 streaming I/O)
    scan_part<<<BSZ * NCH * (DI / 64), 256, 0, stream>>>(
        deltab, xsb, cdb, xp, A_log, D_param, Sbuf);
    scan_fix<<<(BSZ * DI * DS) / 256, 256, 0, stream>>>(Sbuf, cdb, A_log);
    scan_corr<<<BSZ * NCH * (DI / 64), 256, 0, stream>>>(
        deltab, cdb, xp, gb, A_log, Sbuf, yb);

    // d10. out_proj MFMA + residual -> out  [BN=64, 256 blocks — proven]
    gemm_bf16<128, 64, 2><<<dim3(16, 16, 1), 256, 0, stream>>>(
        yb, wOutT, out, MROWS, DM, DI, DI, nullptr, x);
}

// Round 14
// 199.881 us; speedup vs baseline: 1.0103x; 1.0049x over previous
//
#include <hip/hip_runtime.h>
#include <hip/hip_bf16.h>
#include <math.h>

// Problem constants
#define BSZ     2
#define LLEN    1024
#define DM      1024
#define DI      2048
#define DS      16
#define DTR     128
#define NXP     160          // DTR + 2*DS
#define MROWS   (BSZ*LLEN)   // 2048
#define NCH     32           // scan chunks
#define CHL     (LLEN/NCH)   // 32 steps per chunk

typedef short  bf16x8 __attribute__((ext_vector_type(8)));   // 8 bf16 (4 VGPRs)
typedef float  f32x4  __attribute__((ext_vector_type(4)));

__device__ __forceinline__ unsigned short f2bf(float f) {
    unsigned int u = __float_as_uint(f);
    return (unsigned short)((u + 0x7FFFu + ((u >> 16) & 1u)) >> 16);   // RNE
}
__device__ __forceinline__ float bf2f(unsigned short u) {
    return __uint_as_float((unsigned int)u << 16);
}

// ---------------------------------------------------------------------------
// prep: ONE dispatch = LayerNorm->bf16 (blocks 0..2047) + 4 weight
// cast+transposes (blocks 2048..3743). fp32 src[K][N] -> bf16 dst[N][K].
// Full 64x64 tiles take a vectorized unguarded path.
// ---------------------------------------------------------------------------
__global__ __launch_bounds__(256) void prep(
    const float* __restrict__ x, const float* __restrict__ nw,
    const float* __restrict__ nbv, unsigned short* __restrict__ hb,
    const float* __restrict__ w0, unsigned short* __restrict__ t0,
    const float* __restrict__ w1, unsigned short* __restrict__ t1,
    const float* __restrict__ w2, unsigned short* __restrict__ t2,
    const float* __restrict__ w3, unsigned short* __restrict__ t3)
{
    __shared__ unsigned short t[64][68];
    __shared__ float ss[4], sq[4];
    const int tid = threadIdx.x;
    int bid = blockIdx.x;

    if (bid < 2048) {                      // ---- LayerNorm row ----
        const int r = bid;
        const float4 v = ((const float4*)(x + (size_t)r * DM))[tid];
        float s  = v.x + v.y + v.z + v.w;
        float q  = v.x*v.x + v.y*v.y + v.z*v.z + v.w*v.w;
        #pragma unroll
        for (int o = 32; o > 0; o >>= 1) {
            s += __shfl_down(s, o);
            q += __shfl_down(q, o);
        }
        if ((tid & 63) == 0) { ss[tid >> 6] = s; sq[tid >> 6] = q; }
        __syncthreads();
        s = ss[0] + ss[1] + ss[2] + ss[3];
        q = sq[0] + sq[1] + sq[2] + sq[3];
        const float mu  = s * (1.0f / DM);
        const float var = q * (1.0f / DM) - mu * mu;
        const float rs  = rsqrtf(var + 1e-5f);
        const float4 wv = ((const float4*)nw)[tid];
        const float4 bv = ((const float4*)nbv)[tid];
        ushort4 ob;
        ob.x = f2bf((v.x - mu) * rs * wv.x + bv.x);
        ob.y = f2bf((v.y - mu) * rs * wv.y + bv.y);
        ob.z = f2bf((v.z - mu) * rs * wv.z + bv.z);
        ob.w = f2bf((v.w - mu) * rs * wv.w + bv.w);
        *(ushort4*)&hb[(size_t)r * DM + (tid << 2)] = ob;
        return;
    }
    bid -= 2048;                           // ---- transposes ----
    const float* src; unsigned short* dst; int K, N, bx, by;
    if (bid < 1024)      { src = w0; dst = t0; K = 1024; N = 4096;
                           bx = bid & 63; by = bid >> 6; }
    else if (bid < 1120) { int lb = bid - 1024; src = w1; dst = t1;
                           K = 2048; N = 160; bx = lb % 3; by = lb / 3; }
    else if (bid < 1184) { int lb = bid - 1120; src = w2; dst = t2;
                           K = 128; N = 2048; bx = lb & 31; by = lb >> 5; }
    else                 { int lb = bid - 1184; src = w3; dst = t3;
                           K = 2048; N = 1024; bx = lb & 15; by = lb >> 4; }
    const int k0 = by * 64, n0 = bx * 64;
    const bool full = (k0 + 64 <= K) && (n0 + 64 <= N);
    if (full) {
        #pragma unroll
        for (int q = 0; q < 4; ++q) {
            int idx = q * 256 + tid;
            int r = idx >> 4, c = (idx & 15) * 4;
            float4 v = *(const float4*)&src[(size_t)(k0 + r) * N + n0 + c];
            t[r][c]   = f2bf(v.x); t[r][c+1] = f2bf(v.y);
            t[r][c+2] = f2bf(v.z); t[r][c+3] = f2bf(v.w);
        }
        __syncthreads();
        #pragma unroll
        for (int q = 0; q < 4; ++q) {
            int idx = q * 256 + tid;
            int r = idx >> 4, c = (idx & 15) * 4;
            ushort4 o = { t[c][r], t[c+1][r], t[c+2][r], t[c+3][r] };
            *(ushort4*)&dst[(size_t)(n0 + r) * K + k0 + c] = o;
        }
        return;
    }
    #pragma unroll
    for (int q = 0; q < 4; ++q) {
        int idx = q * 256 + tid;
        int r = idx >> 4, c = (idx & 15) * 4;
        if (k0 + r < K) {
            #pragma unroll
            for (int e = 0; e < 4; ++e)
                if (n0 + c + e < N)
                    t[r][c + e] = f2bf(src[(size_t)(k0 + r) * N + n0 + c + e]);
        }
    }
    __syncthreads();
    #pragma unroll
    for (int q = 0; q < 4; ++q) {
        int idx = q * 256 + tid;
        int r = idx >> 4, c = (idx & 15) * 4;
        if (n0 + r < N) {
            #pragma unroll
            for (int e = 0; e < 4; ++e)
                if (k0 + c + e < K)
                    dst[(size_t)(n0 + r) * K + k0 + c + e] = t[c + e][r];
        }
    }
}

// ---------------------------------------------------------------------------
// padded-LDS bf16 MFMA GEMM. 256 thr = 4 waves (2x2).
// EPI: 0 fp32 out, 1 softplus(acc+bias) fp32, 2 +resid fp32,
//      3 bf16 out, 4 softplus(acc+bias) bf16 out,
//      5 split epilogue (in_proj): col<N/2 -> bf16 C; col>=N/2 -> bf16
//        silu into `resid` (cast to ushort*). Both strides N/2.
// Tile note (round-9 lesson): keep BN >= 64 for long-K GEMMs.
// ---------------------------------------------------------------------------
template<int BM, int BN, int EPI>
__global__ __launch_bounds__(256) void gemm_bf16(
    const unsigned short* __restrict__ A,
    const unsigned short* __restrict__ Bt,
    float* __restrict__ C, int M, int N, int K, int kpb,
    const float* __restrict__ bias,
    const float* __restrict__ resid)
{
    constexpr int LDT = 72;
    __shared__ unsigned short As[BM][LDT];
    __shared__ unsigned short Bs[BN][LDT];
    const int tid  = threadIdx.x;
    const int m0   = blockIdx.y * BM;
    const int n0   = blockIdx.x * BN;
    const int kbeg = blockIdx.z * kpb;
    const int kend = kbeg + kpb;
    float* Cw = C + (size_t)blockIdx.z * M * N;
    const int wave = tid >> 6;
    const int lane = tid & 63;
    const int wr   = (wave >> 1) * (BM / 2);
    const int wc   = (wave & 1) * (BN / 2);
    constexpr int FM = BM / 32;
    constexpr int FN = BN / 32;
    const int l15 = lane & 15;
    const int kg  = lane >> 4;

    f32x4 acc[FM][FN] = {};

    for (int kt = kbeg; kt < kend; kt += 64) {
        __syncthreads();
        #pragma unroll
        for (int q = 0; q < BM / 32; ++q) {
            int idx = q * 256 + tid;
            int r = idx >> 3, c = (idx & 7) * 8;
            *(uint4*)&As[r][c] = *(const uint4*)&A[(size_t)(m0 + r) * K + kt + c];
        }
        #pragma unroll
        for (int q = 0; q < BN / 32; ++q) {
            int idx = q * 256 + tid;
            int r = idx >> 3, c = (idx & 7) * 8;
            *(uint4*)&Bs[r][c] = *(const uint4*)&Bt[(size_t)(n0 + r) * K + kt + c];
        }
        __syncthreads();
        #pragma unroll
        for (int ks = 0; ks < 2; ++ks) {
            bf16x8 af[FM], bfr[FN];
            #pragma unroll
            for (int i = 0; i < FM; ++i)
                af[i] = *(const bf16x8*)&As[wr + i * 16 + l15][ks * 32 + kg * 8];
            #pragma unroll
            for (int j = 0; j < FN; ++j)
                bfr[j] = *(const bf16x8*)&Bs[wc + j * 16 + l15][ks * 32 + kg * 8];
            #pragma unroll
            for (int i = 0; i < FM; ++i)
                #pragma unroll
                for (int j = 0; j < FN; ++j)
                    acc[i][j] = __builtin_amdgcn_mfma_f32_16x16x32_bf16(
                        af[i], bfr[j], acc[i][j], 0, 0, 0);
        }
    }
    // C/D layout: col = lane&15, row = (lane>>4)*4 + reg   [m89-verified]
    #pragma unroll
    for (int i = 0; i < FM; ++i) {
        #pragma unroll
        for (int j = 0; j < FN; ++j) {
            const int row = m0 + wr + i * 16 + kg * 4;
            const int col = n0 + wc + j * 16 + l15;
            #pragma unroll
            for (int r = 0; r < 4; ++r) {
                float v = acc[i][j][r];
                if (EPI == 1 || EPI == 4) {
                    float t = v + bias[col];
                    v = (t > 20.f) ? t : log1pf(__expf(t));
                } else if (EPI == 2) {
                    v += resid[(size_t)(row + r) * N + col];
                }
                if (EPI == 5) {
                    const int half = N >> 1;
                    if (col < half) {
                        ((unsigned short*)Cw)[(size_t)(row + r) * half + col] = f2bf(v);
                    } else {
                        const float sig = v / (1.f + __expf(-v));
                        ((unsigned short*)resid)[(size_t)(row + r) * half + (col - half)] = f2bf(sig);
                    }
                } else if (EPI == 3 || EPI == 4) {
                    ((unsigned short*)Cw)[(size_t)(row + r) * N + col] = f2bf(v);
                } else {
                    Cw[(size_t)(row + r) * N + col] = v;
                }
            }
        }
    }
}

// ---------------------------------------------------------------------------
// x_proj split-K reduce: sum 4 partials; write xp fp32 + dr bf16 (cols<128)
// ---------------------------------------------------------------------------
__global__ __launch_bounds__(256) void xproj_reduce(
    const float* __restrict__ P4, float* __restrict__ xp,
    unsigned short* __restrict__ drb)
{
    const int idx = blockIdx.x * 256 + threadIdx.x;   // < 2048*160
    float s = 0.f;
    #pragma unroll
    for (int j = 0; j < 4; ++j)
        s += P4[(size_t)j * (MROWS * NXP) + idx];
    xp[idx] = s;
    const int row = idx / NXP, col = idx - row * NXP;
    if (col < DTR) drb[(size_t)row * DTR + col] = f2bf(s);
}

// ---------------------------------------------------------------------------
// causal depthwise conv (K=4) + SiLU over bf16 xr (xs half only, 2048 cols).
// Vectorized: 4 channels/thread, ushort4 loads/stores.
// ---------------------------------------------------------------------------
__global__ __launch_bounds__(256) void conv_silu(
    const unsigned short* __restrict__ xrb, const float* __restrict__ cw,
    const float* __restrict__ cb, unsigned short* __restrict__ xsb)
{
    const int idx = blockIdx.x * 256 + threadIdx.x;   // over 2*1024*512 quads
    const int d0 = (idx & 511) << 2;                  // channel base (x4)
    const int t  = (idx >> 9) & (LLEN - 1);
    const int b  = idx >> 19;
    float4 wv[4];
    #pragma unroll
    for (int e = 0; e < 4; ++e) wv[e] = ((const float4*)cw)[d0 + e];
    float acc[4];
    #pragma unroll
    for (int e = 0; e < 4; ++e) acc[e] = cb[d0 + e];
    #pragma unroll
    for (int k = 0; k < 4; ++k) {
        const int tt = t + k - 3;
        if (tt >= 0) {
            const ushort4 xv = *(const ushort4*)
                &xrb[((size_t)(b * LLEN + tt) << 11) + d0];
            acc[0] = fmaf((&wv[0].x)[k], bf2f(xv.x), acc[0]);
            acc[1] = fmaf((&wv[1].x)[k], bf2f(xv.y), acc[1]);
            acc[2] = fmaf((&wv[2].x)[k], bf2f(xv.z), acc[2]);
            acc[3] = fmaf((&wv[3].x)[k], bf2f(xv.w), acc[3]);
        }
    }
    ushort4 o;
    o.x = f2bf(acc[0] / (1.f + __expf(-acc[0])) * 1.f);
    o.y = f2bf(acc[1] / (1.f + __expf(-acc[1])) * 1.f);
    o.z = f2bf(acc[2] / (1.f + __expf(-acc[2])) * 1.f);
    o.w = f2bf(acc[3] / (1.f + __expf(-acc[3])) * 1.f);
    *(ushort4*)&xsb[((size_t)(b * LLEN + t) << 11) + d0] = o;
}

// ---------------------------------------------------------------------------
// Scan pass A: 4 threads per channel (4 states each). Walks chunk with h0=0.
// bf16 I/O: dio (bf16 delta in / y' out, in-place), cd bf16 cumDelta,
// u from bf16 xsb. S (fp32) = chunk-final h.
// ---------------------------------------------------------------------------
__global__ __launch_bounds__(256) void scan_part(
    unsigned short* __restrict__ dio, const unsigned short* __restrict__ ub,
    unsigned short* __restrict__ cd, const float* __restrict__ xp,
    const float* __restrict__ A_log, const float* __restrict__ Dp,
    float* __restrict__ S)
{
    const int blk  = blockIdx.x;               // BSZ*NCH*32 = 2048
    const int dgrp = blk & 31;                 // 32 groups of 64 channels
    const int j    = (blk >> 5) & (NCH - 1);
    const int b    = blk >> 10;
    const int c    = threadIdx.x >> 2;         // local channel 0..63
    const int sg   = threadIdx.x & 3;          // state group
    const int d    = dgrp * 64 + c;
    const int nb   = sg * 4;
    float aL[4], h[4];
    #pragma unroll
    for (int n = 0; n < 4; ++n) {
        aL[n] = -__expf(A_log[d * DS + nb + n]) * 1.44269504088896f;
        h[n] = 0.f;
    }
    const float Dd = Dp[d];
    float sd = 0.f;
    const int t0 = j * CHL;
    for (int t = t0; t < t0 + CHL; ++t) {
        const size_t row = (size_t)(b * LLEN + t);
        const float dlt = bf2f(dio[row * DI + d]);
        const float u   = bf2f(ub[row * DI + d]);
        const float du  = dlt * u;
        sd += dlt;
        const float* Bp = &xp[row * NXP + DTR + nb];
        const float* Cp = &xp[row * NXP + DTR + DS + nb];
        float y = sg ? 0.f : Dd * u;
        #pragma unroll
        for (int n = 0; n < 4; ++n) {
            const float dA = exp2f(dlt * aL[n]);
            h[n] = fmaf(dA, h[n], du * Bp[n]);
            y = fmaf(h[n], Cp[n], y);
        }
        y += __shfl_xor(y, 1);
        y += __shfl_xor(y, 2);
        if (!sg) {
            dio[row * DI + d] = f2bf(y);       // y' (partial, h0=0)
            cd[row * DI + d]  = f2bf(sd);      // inclusive cumulative delta
        }
    }
    float* So = &S[(((size_t)j * BSZ + b) * DI + d) * DS + nb];
    #pragma unroll
    for (int n = 0; n < 4; ++n) So[n] = h[n];
}

// ---------------------------------------------------------------------------
// Scan pass B: inter-chunk fix-up, thread per (b,d,n). cd bf16.
// ---------------------------------------------------------------------------
__global__ __launch_bounds__(256) void scan_fix(
    float* __restrict__ S, const unsigned short* __restrict__ cumD,
    const float* __restrict__ A_log)
{
    const int c = blockIdx.x * 256 + threadIdx.x;   // < 2*2048*16
    const int n = c & 15;
    const int d = (c >> 4) & (DI - 1);
    const int b = c >> 15;
    const float aL = -__expf(A_log[d * DS + n]) * 1.44269504088896f;
    float h = 0.f;
    #pragma unroll
    for (int j = 0; j < NCH; ++j) {
        const float sd = bf2f(cumD[(size_t)(b * LLEN + j * CHL + CHL - 1) * DI + d]);
        const size_t base = (((size_t)j * BSZ + b) * DI + d) * DS + n;
        const float Pj = exp2f(aL * sd);
        const float Sj = S[base];
        S[base] = h;
        h = fmaf(Pj, h, Sj);
    }
}

// ---------------------------------------------------------------------------
// Scan pass C (correction, no recurrence): 4 threads per channel. bf16 I/O.
//   y_t = y'_t + sum_n C_t[n]*exp2(aL[n]*cumD_t)*H0[n];  yb = bf16(y*g)
// ---------------------------------------------------------------------------
__global__ __launch_bounds__(256) void scan_corr(
    const unsigned short* __restrict__ yp, const unsigned short* __restrict__ cumD,
    const float* __restrict__ xp, const unsigned short* __restrict__ gb,
    const float* __restrict__ A_log, const float* __restrict__ H0,
    unsigned short* __restrict__ yb)
{
    const int blk  = blockIdx.x;               // 2048
    const int dgrp = blk & 31;
    const int j    = (blk >> 5) & (NCH - 1);
    const int b    = blk >> 10;
    const int c    = threadIdx.x >> 2;
    const int sg   = threadIdx.x & 3;
    const int d    = dgrp * 64 + c;
    const int nb   = sg * 4;
    float aL[4], H[4];
    const float* Hp = &H0[(((size_t)j * BSZ + b) * DI + d) * DS + nb];
    #pragma unroll
    for (int n = 0; n < 4; ++n) {
        aL[n] = -__expf(A_log[d * DS + nb + n]) * 1.44269504088896f;
        H[n] = Hp[n];
    }
    const int t0 = j * CHL;
    for (int t = t0; t < t0 + CHL; ++t) {
        const size_t row = (size_t)(b * LLEN + t);
        const float cdv = bf2f(cumD[row * DI + d]);
        const float* Cp = &xp[row * NXP + DTR + DS + nb];
        float corr = 0.f;
        #pragma unroll
        for (int n = 0; n < 4; ++n)
            corr = fmaf(H[n] * exp2f(aL[n] * cdv), Cp[n], corr);
        corr += __shfl_xor(corr, 1);
        corr += __shfl_xor(corr, 2);
        if (!sg) {
            const float y = bf2f(yp[row * DI + d]) + corr;
            yb[row * DI + d] = f2bf(y * bf2f(gb[row * DI + d]));
        }
    }
}

// ---------------------------------------------------------------------------
extern "C" void kernel_launch(void* const* d_in, const int* in_sizes, int n_in,
                              void* d_out, int out_size, void* d_ws, size_t ws_size,
                              hipStream_t stream)
{
    (void)in_sizes; (void)n_in; (void)out_size; (void)ws_size;
    const float* x         = (const float*)d_in[0];
    const float* norm_w    = (const float*)d_in[1];
    const float* norm_b    = (const float*)d_in[2];
    const float* in_proj_w = (const float*)d_in[3];   // (1024, 4096)
    const float* conv_w    = (const float*)d_in[4];
    const float* conv_b    = (const float*)d_in[5];
    const float* x_proj_w  = (const float*)d_in[6];   // (2048, 160)
    const float* dt_proj_w = (const float*)d_in[7];   // (128, 2048)
    const float* dt_proj_b = (const float*)d_in[8];
    const float* A_log     = (const float*)d_in[9];
    const float* D_param   = (const float*)d_in[10];
    const float* out_proj_w= (const float*)d_in[11];  // (2048, 1024)
    float* out = (float*)d_out;

    // Workspace overlays (per-dispatch liveness audited):
    //   d1 prep:      writes hb, wInT, wXT, dtwT, wOutT
    //   d2 in_proj:   hb,wInT -> xrb bf16 (0..8M, xs half) + gb (8.39M, gate)
    //   d3 conv:      xrb -> xsb(67.1M)
    //   d4 x_proj:    xsb,wXT -> P4(0..5.25M; xrb dead)
    //   d5 reduce:    P4 -> xp(25.2M), drb(27.3M)
    //   d6 dt_proj:   drb,dtwT -> deltab bf16 (0..8M)
    //   d7 scan_part: deltab(in-place y'), xsb, xp -> cdb(33.5M), Sbuf(16.8M)
    //   d8 scan_fix:  Sbuf, cdb
    //   d9 scan_corr: deltab,cdb,xp,gb,Sbuf -> yb(67.1M over dead xsb)
    //   d10 out_proj: yb,wOutT(62.9M),x -> out
    char* ws = (char*)d_ws;
    unsigned short* xrb    = (unsigned short*)(ws);             // 8M   d2..d3
    float*          P4     = (float*)(ws);                      // 5.25M d4..d5
    unsigned short* deltab = (unsigned short*)(ws);             // 8M   d6..d9
    unsigned short* gb     = (unsigned short*)(ws + 8388608);   // 8M   d2..d9
    float*          Sbuf   = (float*)(ws + 16777216);           // 8M   d7..d9
    float*          xp     = (float*)(ws + 25165824);           // 1.25M d5..d9
    unsigned short* drb    = (unsigned short*)(ws + 27262976);  // 512K d5..d6
    unsigned short* cdb    = (unsigned short*)(ws + 33554432);  // 8M   d7..d9
    unsigned short* wInT   = (unsigned short*)(ws + 50331648);  // 8M   d1..d2
    unsigned short* hb     = (unsigned short*)(ws + 58720256);  // 4M   d1..d2
    unsigned short* wOutT  = (unsigned short*)(ws + 62914560);  // 4M   d1..d10
    unsigned short* xsb    = (unsigned short*)(ws + 67108864);  // 8M   d3..d7
    unsigned short* yb     = (unsigned short*)(ws + 67108864);  // 8M   d9..d10
    unsigned short* wXT    = (unsigned short*)(ws + 75497472);  // 640K d1..d4
    unsigned short* dtwT   = (unsigned short*)(ws + 76152832);  // 512K d1..d6

    // d1. LN + all four weight transposes, one dispatch
    prep<<<3744, 256, 0, stream>>>(x, norm_w, norm_b, hb,
                                   in_proj_w, wInT, x_proj_w, wXT,
                                   dt_proj_w, dtwT, out_proj_w, wOutT);

    // d2. in_proj with split epilogue: xs half -> xrb bf16; gate -> gb silu bf16
    gemm_bf16<128, 128, 5><<<dim3(32, 16, 1), 256, 0, stream>>>(
        hb, wInT, (float*)xrb, MROWS, 2 * DI, DM, DM, nullptr, (const float*)gb);

    // d3. conv + silu over bf16 xr (xs half only) -> xsb bf16  [vectorized x4]
    conv_silu<<<(BSZ * LLEN * DI / 4) / 256, 256, 0, stream>>>(
        xrb, conv_w, conv_b, xsb);

    // d4. x_proj MFMA split-K=4 -> P4 partials  [320 blocks, 8 K-steps each]
    gemm_bf16<128, 32, 0><<<dim3(5, 16, 4), 256, 0, stream>>>(
        xsb, wXT, P4, MROWS, NXP, DI, DI / 4, nullptr, nullptr);
    // d5. reduce -> xp fp32, drb bf16
    xproj_reduce<<<(MROWS * NXP) / 256, 256, 0, stream>>>(P4, xp, drb);

    // d6. dt_proj MFMA + softplus -> deltab bf16  [EPI=4]
    gemm_bf16<128, 64, 4><<<dim3(32, 16, 1), 256, 0, stream>>>(
        drb, dtwT, (float*)deltab, MROWS, DI, DTR, DTR, dt_proj_b, nullptr);

    // d7-d9. chunked selective scan (bf16 streaming I/O)
    scan_part<<<BSZ * NCH * (DI / 64), 256, 0, stream>>>(
        deltab, xsb, cdb, xp, A_log, D_param, Sbuf);
    scan_fix<<<(BSZ * DI * DS) / 256, 256, 0, stream>>>(Sbuf, cdb, A_log);
    scan_corr<<<BSZ * NCH * (DI / 64), 256, 0, stream>>>(
        deltab, cdb, xp, gb, A_log, Sbuf, yb);

    // d10. out_proj MFMA + residual -> out  [BN=64, 256 blocks — proven]
    gemm_bf16<128, 64, 2><<<dim3(16, 16, 1), 256, 0, stream>>>(
        yb, wOutT, out, MROWS, DM, DI, DI, nullptr, x);
}

// Round 15
// 197.228 us; speedup vs baseline: 1.0239x; 1.0135x over previous
//
#include <hip/hip_runtime.h>
#include <hip/hip_bf16.h>
#include <math.h>

// Problem constants
#define BSZ     2
#define LLEN    1024
#define DM      1024
#define DI      2048
#define DS      16
#define DTR     128
#define NXP     160          // DTR + 2*DS
#define MROWS   (BSZ*LLEN)   // 2048
#define NCH     64           // scan chunks
#define CHL     (LLEN/NCH)   // 16 steps per chunk
#define SKX     8            // x_proj split-K factor

typedef short  bf16x8 __attribute__((ext_vector_type(8)));   // 8 bf16 (4 VGPRs)
typedef float  f32x4  __attribute__((ext_vector_type(4)));

__device__ __forceinline__ unsigned short f2bf(float f) {
    unsigned int u = __float_as_uint(f);
    return (unsigned short)((u + 0x7FFFu + ((u >> 16) & 1u)) >> 16);   // RNE
}
__device__ __forceinline__ float bf2f(unsigned short u) {
    return __uint_as_float((unsigned int)u << 16);
}

// ---------------------------------------------------------------------------
// prep: ONE dispatch = LayerNorm->bf16 (blocks 0..2047) + 4 weight
// cast+transposes (blocks 2048..3743). fp32 src[K][N] -> bf16 dst[N][K].
// Full 64x64 tiles take a vectorized unguarded path.
// ---------------------------------------------------------------------------
__global__ __launch_bounds__(256) void prep(
    const float* __restrict__ x, const float* __restrict__ nw,
    const float* __restrict__ nbv, unsigned short* __restrict__ hb,
    const float* __restrict__ w0, unsigned short* __restrict__ t0,
    const float* __restrict__ w1, unsigned short* __restrict__ t1,
    const float* __restrict__ w2, unsigned short* __restrict__ t2,
    const float* __restrict__ w3, unsigned short* __restrict__ t3)
{
    __shared__ unsigned short t[64][68];
    __shared__ float ss[4], sq[4];
    const int tid = threadIdx.x;
    int bid = blockIdx.x;

    if (bid < 2048) {                      // ---- LayerNorm row ----
        const int r = bid;
        const float4 v = ((const float4*)(x + (size_t)r * DM))[tid];
        float s  = v.x + v.y + v.z + v.w;
        float q  = v.x*v.x + v.y*v.y + v.z*v.z + v.w*v.w;
        #pragma unroll
        for (int o = 32; o > 0; o >>= 1) {
            s += __shfl_down(s, o);
            q += __shfl_down(q, o);
        }
        if ((tid & 63) == 0) { ss[tid >> 6] = s; sq[tid >> 6] = q; }
        __syncthreads();
        s = ss[0] + ss[1] + ss[2] + ss[3];
        q = sq[0] + sq[1] + sq[2] + sq[3];
        const float mu  = s * (1.0f / DM);
        const float var = q * (1.0f / DM) - mu * mu;
        const float rs  = rsqrtf(var + 1e-5f);
        const float4 wv = ((const float4*)nw)[tid];
        const float4 bv = ((const float4*)nbv)[tid];
        ushort4 ob;
        ob.x = f2bf((v.x - mu) * rs * wv.x + bv.x);
        ob.y = f2bf((v.y - mu) * rs * wv.y + bv.y);
        ob.z = f2bf((v.z - mu) * rs * wv.z + bv.z);
        ob.w = f2bf((v.w - mu) * rs * wv.w + bv.w);
        *(ushort4*)&hb[(size_t)r * DM + (tid << 2)] = ob;
        return;
    }
    bid -= 2048;                           // ---- transposes ----
    const float* src; unsigned short* dst; int K, N, bx, by;
    if (bid < 1024)      { src = w0; dst = t0; K = 1024; N = 4096;
                           bx = bid & 63; by = bid >> 6; }
    else if (bid < 1120) { int lb = bid - 1024; src = w1; dst = t1;
                           K = 2048; N = 160; bx = lb % 3; by = lb / 3; }
    else if (bid < 1184) { int lb = bid - 1120; src = w2; dst = t2;
                           K = 128; N = 2048; bx = lb & 31; by = lb >> 5; }
    else                 { int lb = bid - 1184; src = w3; dst = t3;
                           K = 2048; N = 1024; bx = lb & 15; by = lb >> 4; }
    const int k0 = by * 64, n0 = bx * 64;
    const bool full = (k0 + 64 <= K) && (n0 + 64 <= N);
    if (full) {
        #pragma unroll
        for (int q = 0; q < 4; ++q) {
            int idx = q * 256 + tid;
            int r = idx >> 4, c = (idx & 15) * 4;
            float4 v = *(const float4*)&src[(size_t)(k0 + r) * N + n0 + c];
            t[r][c]   = f2bf(v.x); t[r][c+1] = f2bf(v.y);
            t[r][c+2] = f2bf(v.z); t[r][c+3] = f2bf(v.w);
        }
        __syncthreads();
        #pragma unroll
        for (int q = 0; q < 4; ++q) {
            int idx = q * 256 + tid;
            int r = idx >> 4, c = (idx & 15) * 4;
            ushort4 o = { t[c][r], t[c+1][r], t[c+2][r], t[c+3][r] };
            *(ushort4*)&dst[(size_t)(n0 + r) * K + k0 + c] = o;
        }
        return;
    }
    #pragma unroll
    for (int q = 0; q < 4; ++q) {
        int idx = q * 256 + tid;
        int r = idx >> 4, c = (idx & 15) * 4;
        if (k0 + r < K) {
            #pragma unroll
            for (int e = 0; e < 4; ++e)
                if (n0 + c + e < N)
                    t[r][c + e] = f2bf(src[(size_t)(k0 + r) * N + n0 + c + e]);
        }
    }
    __syncthreads();
    #pragma unroll
    for (int q = 0; q < 4; ++q) {
        int idx = q * 256 + tid;
        int r = idx >> 4, c = (idx & 15) * 4;
        if (n0 + r < N) {
            #pragma unroll
            for (int e = 0; e < 4; ++e)
                if (k0 + c + e < K)
                    dst[(size_t)(n0 + r) * K + k0 + c + e] = t[c + e][r];
        }
    }
}

// ---------------------------------------------------------------------------
// padded-LDS bf16 MFMA GEMM. 256 thr = 4 waves (2x2).
// EPI: 0 fp32 out, 1 softplus(acc+bias) fp32, 2 +resid fp32,
//      3 bf16 out, 4 softplus(acc+bias) bf16 out,
//      5 split epilogue (in_proj): col<N/2 -> bf16 C; col>=N/2 -> bf16
//        silu into `resid` (cast to ushort*). Both strides N/2.
// Tile note (round-9 lesson): keep BN >= 64 for long-K GEMMs.
// ---------------------------------------------------------------------------
template<int BM, int BN, int EPI>
__global__ __launch_bounds__(256) void gemm_bf16(
    const unsigned short* __restrict__ A,
    const unsigned short* __restrict__ Bt,
    float* __restrict__ C, int M, int N, int K, int kpb,
    const float* __restrict__ bias,
    const float* __restrict__ resid)
{
    constexpr int LDT = 72;
    __shared__ unsigned short As[BM][LDT];
    __shared__ unsigned short Bs[BN][LDT];
    const int tid  = threadIdx.x;
    const int m0   = blockIdx.y * BM;
    const int n0   = blockIdx.x * BN;
    const int kbeg = blockIdx.z * kpb;
    const int kend = kbeg + kpb;
    float* Cw = C + (size_t)blockIdx.z * M * N;
    const int wave = tid >> 6;
    const int lane = tid & 63;
    const int wr   = (wave >> 1) * (BM / 2);
    const int wc   = (wave & 1) * (BN / 2);
    constexpr int FM = BM / 32;
    constexpr int FN = BN / 32;
    const int l15 = lane & 15;
    const int kg  = lane >> 4;

    f32x4 acc[FM][FN] = {};

    for (int kt = kbeg; kt < kend; kt += 64) {
        __syncthreads();
        #pragma unroll
        for (int q = 0; q < BM / 32; ++q) {
            int idx = q * 256 + tid;
            int r = idx >> 3, c = (idx & 7) * 8;
            *(uint4*)&As[r][c] = *(const uint4*)&A[(size_t)(m0 + r) * K + kt + c];
        }
        #pragma unroll
        for (int q = 0; q < BN / 32; ++q) {
            int idx = q * 256 + tid;
            int r = idx >> 3, c = (idx & 7) * 8;
            *(uint4*)&Bs[r][c] = *(const uint4*)&Bt[(size_t)(n0 + r) * K + kt + c];
        }
        __syncthreads();
        #pragma unroll
        for (int ks = 0; ks < 2; ++ks) {
            bf16x8 af[FM], bfr[FN];
            #pragma unroll
            for (int i = 0; i < FM; ++i)
                af[i] = *(const bf16x8*)&As[wr + i * 16 + l15][ks * 32 + kg * 8];
            #pragma unroll
            for (int j = 0; j < FN; ++j)
                bfr[j] = *(const bf16x8*)&Bs[wc + j * 16 + l15][ks * 32 + kg * 8];
            #pragma unroll
            for (int i = 0; i < FM; ++i)
                #pragma unroll
                for (int j = 0; j < FN; ++j)
                    acc[i][j] = __builtin_amdgcn_mfma_f32_16x16x32_bf16(
                        af[i], bfr[j], acc[i][j], 0, 0, 0);
        }
    }
    // C/D layout: col = lane&15, row = (lane>>4)*4 + reg   [m89-verified]
    #pragma unroll
    for (int i = 0; i < FM; ++i) {
        #pragma unroll
        for (int j = 0; j < FN; ++j) {
            const int row = m0 + wr + i * 16 + kg * 4;
            const int col = n0 + wc + j * 16 + l15;
            #pragma unroll
            for (int r = 0; r < 4; ++r) {
                float v = acc[i][j][r];
                if (EPI == 1 || EPI == 4) {
                    float t = v + bias[col];
                    v = (t > 20.f) ? t : log1pf(__expf(t));
                } else if (EPI == 2) {
                    v += resid[(size_t)(row + r) * N + col];
                }
                if (EPI == 5) {
                    const int half = N >> 1;
                    if (col < half) {
                        ((unsigned short*)Cw)[(size_t)(row + r) * half + col] = f2bf(v);
                    } else {
                        const float sig = v / (1.f + __expf(-v));
                        ((unsigned short*)resid)[(size_t)(row + r) * half + (col - half)] = f2bf(sig);
                    }
                } else if (EPI == 3 || EPI == 4) {
                    ((unsigned short*)Cw)[(size_t)(row + r) * N + col] = f2bf(v);
                } else {
                    Cw[(size_t)(row + r) * N + col] = v;
                }
            }
        }
    }
}

// ---------------------------------------------------------------------------
// x_proj split-K reduce: sum SKX partials; write xp fp32 + dr bf16 (cols<128)
// ---------------------------------------------------------------------------
__global__ __launch_bounds__(256) void xproj_reduce(
    const float* __restrict__ P, float* __restrict__ xp,
    unsigned short* __restrict__ drb)
{
    const int idx = blockIdx.x * 256 + threadIdx.x;   // < 2048*160
    float s = 0.f;
    #pragma unroll
    for (int j = 0; j < SKX; ++j)
        s += P[(size_t)j * (MROWS * NXP) + idx];
    xp[idx] = s;
    const int row = idx / NXP, col = idx - row * NXP;
    if (col < DTR) drb[(size_t)row * DTR + col] = f2bf(s);
}

// ---------------------------------------------------------------------------
// causal depthwise conv (K=4) + SiLU over bf16 xr (xs half only, 2048 cols).
// Vectorized: 4 channels/thread, ushort4 loads/stores.
// ---------------------------------------------------------------------------
__global__ __launch_bounds__(256) void conv_silu(
    const unsigned short* __restrict__ xrb, const float* __restrict__ cw,
    const float* __restrict__ cb, unsigned short* __restrict__ xsb)
{
    const int idx = blockIdx.x * 256 + threadIdx.x;   // over 2*1024*512 quads
    const int d0 = (idx & 511) << 2;                  // channel base (x4)
    const int t  = (idx >> 9) & (LLEN - 1);
    const int b  = idx >> 19;
    float4 wv[4];
    #pragma unroll
    for (int e = 0; e < 4; ++e) wv[e] = ((const float4*)cw)[d0 + e];
    float acc[4];
    #pragma unroll
    for (int e = 0; e < 4; ++e) acc[e] = cb[d0 + e];
    #pragma unroll
    for (int k = 0; k < 4; ++k) {
        const int tt = t + k - 3;
        if (tt >= 0) {
            const ushort4 xv = *(const ushort4*)
                &xrb[((size_t)(b * LLEN + tt) << 11) + d0];
            acc[0] = fmaf((&wv[0].x)[k], bf2f(xv.x), acc[0]);
            acc[1] = fmaf((&wv[1].x)[k], bf2f(xv.y), acc[1]);
            acc[2] = fmaf((&wv[2].x)[k], bf2f(xv.z), acc[2]);
            acc[3] = fmaf((&wv[3].x)[k], bf2f(xv.w), acc[3]);
        }
    }
    ushort4 o;
    o.x = f2bf(acc[0] / (1.f + __expf(-acc[0])));
    o.y = f2bf(acc[1] / (1.f + __expf(-acc[1])));
    o.z = f2bf(acc[2] / (1.f + __expf(-acc[2])));
    o.w = f2bf(acc[3] / (1.f + __expf(-acc[3])));
    *(ushort4*)&xsb[((size_t)(b * LLEN + t) << 11) + d0] = o;
}

// ---------------------------------------------------------------------------
// Scan pass A: 4 threads per channel (4 states each). NCH=64 chunks of 16.
// bf16 I/O: dio (bf16 delta in / y' out, in-place), cd bf16 cumDelta,
// u from bf16 xsb. S (fp32) = chunk-final h.
// ---------------------------------------------------------------------------
__global__ __launch_bounds__(256) void scan_part(
    unsigned short* __restrict__ dio, const unsigned short* __restrict__ ub,
    unsigned short* __restrict__ cd, const float* __restrict__ xp,
    const float* __restrict__ A_log, const float* __restrict__ Dp,
    float* __restrict__ S)
{
    const int blk  = blockIdx.x;               // BSZ*NCH*32 = 4096
    const int dgrp = blk & 31;                 // 32 groups of 64 channels
    const int j    = (blk >> 5) & (NCH - 1);   // chunk 0..63
    const int b    = blk >> 11;
    const int c    = threadIdx.x >> 2;         // local channel 0..63
    const int sg   = threadIdx.x & 3;          // state group
    const int d    = dgrp * 64 + c;
    const int nb   = sg * 4;
    float aL[4], h[4];
    #pragma unroll
    for (int n = 0; n < 4; ++n) {
        aL[n] = -__expf(A_log[d * DS + nb + n]) * 1.44269504088896f;
        h[n] = 0.f;
    }
    const float Dd = Dp[d];
    float sd = 0.f;
    const int t0 = j * CHL;
    for (int t = t0; t < t0 + CHL; ++t) {
        const size_t row = (size_t)(b * LLEN + t);
        const float dlt = bf2f(dio[row * DI + d]);
        const float u   = bf2f(ub[row * DI + d]);
        const float du  = dlt * u;
        sd += dlt;
        const float* Bp = &xp[row * NXP + DTR + nb];
        const float* Cp = &xp[row * NXP + DTR + DS + nb];
        float y = sg ? 0.f : Dd * u;
        #pragma unroll
        for (int n = 0; n < 4; ++n) {
            const float dA = exp2f(dlt * aL[n]);
            h[n] = fmaf(dA, h[n], du * Bp[n]);
            y = fmaf(h[n], Cp[n], y);
        }
        y += __shfl_xor(y, 1);
        y += __shfl_xor(y, 2);
        if (!sg) {
            dio[row * DI + d] = f2bf(y);       // y' (partial, h0=0)
            cd[row * DI + d]  = f2bf(sd);      // inclusive cumulative delta
        }
    }
    float* So = &S[(((size_t)j * BSZ + b) * DI + d) * DS + nb];
    #pragma unroll
    for (int n = 0; n < 4; ++n) So[n] = h[n];
}

// ---------------------------------------------------------------------------
// Scan pass B: inter-chunk fix-up, thread per (b,d,n). cd bf16. NCH=64 chain.
// ---------------------------------------------------------------------------
__global__ __launch_bounds__(256) void scan_fix(
    float* __restrict__ S, const unsigned short* __restrict__ cumD,
    const float* __restrict__ A_log)
{
    const int c = blockIdx.x * 256 + threadIdx.x;   // < 2*2048*16
    const int n = c & 15;
    const int d = (c >> 4) & (DI - 1);
    const int b = c >> 15;
    const float aL = -__expf(A_log[d * DS + n]) * 1.44269504088896f;
    float h = 0.f;
    #pragma unroll 8
    for (int j = 0; j < NCH; ++j) {
        const float sd = bf2f(cumD[(size_t)(b * LLEN + j * CHL + CHL - 1) * DI + d]);
        const size_t base = (((size_t)j * BSZ + b) * DI + d) * DS + n;
        const float Pj = exp2f(aL * sd);
        const float Sj = S[base];
        S[base] = h;
        h = fmaf(Pj, h, Sj);
    }
}

// ---------------------------------------------------------------------------
// Scan pass C (correction, no recurrence): 4 threads per channel. bf16 I/O.
//   y_t = y'_t + sum_n C_t[n]*exp2(aL[n]*cumD_t)*H0[n];  yb = bf16(y*g)
// ---------------------------------------------------------------------------
__global__ __launch_bounds__(256) void scan_corr(
    const unsigned short* __restrict__ yp, const unsigned short* __restrict__ cumD,
    const float* __restrict__ xp, const unsigned short* __restrict__ gb,
    const float* __restrict__ A_log, const float* __restrict__ H0,
    unsigned short* __restrict__ yb)
{
    const int blk  = blockIdx.x;               // 4096
    const int dgrp = blk & 31;
    const int j    = (blk >> 5) & (NCH - 1);
    const int b    = blk >> 11;
    const int c    = threadIdx.x >> 2;
    const int sg   = threadIdx.x & 3;
    const int d    = dgrp * 64 + c;
    const int nb   = sg * 4;
    float aL[4], H[4];
    const float* Hp = &H0[(((size_t)j * BSZ + b) * DI + d) * DS + nb];
    #pragma unroll
    for (int n = 0; n < 4; ++n) {
        aL[n] = -__expf(A_log[d * DS + nb + n]) * 1.44269504088896f;
        H[n] = Hp[n];
    }
    const int t0 = j * CHL;
    for (int t = t0; t < t0 + CHL; ++t) {
        const size_t row = (size_t)(b * LLEN + t);
        const float cdv = bf2f(cumD[row * DI + d]);
        const float* Cp = &xp[row * NXP + DTR + DS + nb];
        float corr = 0.f;
        #pragma unroll
        for (int n = 0; n < 4; ++n)
            corr = fmaf(H[n] * exp2f(aL[n] * cdv), Cp[n], corr);
        corr += __shfl_xor(corr, 1);
        corr += __shfl_xor(corr, 2);
        if (!sg) {
            const float y = bf2f(yp[row * DI + d]) + corr;
            yb[row * DI + d] = f2bf(y * bf2f(gb[row * DI + d]));
        }
    }
}

// ---------------------------------------------------------------------------
extern "C" void kernel_launch(void* const* d_in, const int* in_sizes, int n_in,
                              void* d_out, int out_size, void* d_ws, size_t ws_size,
                              hipStream_t stream)
{
    (void)in_sizes; (void)n_in; (void)out_size; (void)ws_size;
    const float* x         = (const float*)d_in[0];
    const float* norm_w    = (const float*)d_in[1];
    const float* norm_b    = (const float*)d_in[2];
    const float* in_proj_w = (const float*)d_in[3];   // (1024, 4096)
    const float* conv_w    = (const float*)d_in[4];
    const float* conv_b    = (const float*)d_in[5];
    const float* x_proj_w  = (const float*)d_in[6];   // (2048, 160)
    const float* dt_proj_w = (const float*)d_in[7];   // (128, 2048)
    const float* dt_proj_b = (const float*)d_in[8];
    const float* A_log     = (const float*)d_in[9];
    const float* D_param   = (const float*)d_in[10];
    const float* out_proj_w= (const float*)d_in[11];  // (2048, 1024)
    float* out = (float*)d_out;

    // Workspace overlays (per-dispatch liveness audited):
    //   d1 prep:      writes hb, wInT, wXT, dtwT, wOutT
    //   d2 in_proj:   hb,wInT -> xrb bf16 (0..8M) + gb (8.39M, gate)
    //   d3 conv:      xrb -> xsb(67.1M)
    //   d4 x_proj:    xsb,wXT -> P8(27.79M..38.27M; time-disjoint from cdb d7+)
    //   d5 reduce:    P8 -> xp(25.2M), drb(27.26M, below P8)
    //   d6 dt_proj:   drb,dtwT -> deltab bf16 (0..8M)
    //   d7 scan_part: deltab(in-place y'), xsb, xp -> cdb(33.5M), Sbuf(41.94M,
    //                 16.78M — overlaps only wInT which is dead after d2)
    //   d8 scan_fix:  Sbuf, cdb
    //   d9 scan_corr: deltab,cdb,xp,gb,Sbuf -> yb(67.1M over dead xsb)
    //   d10 out_proj: yb,wOutT(62.9M),x -> out
    char* ws = (char*)d_ws;
    unsigned short* xrb    = (unsigned short*)(ws);             // 8M   d2..d3
    unsigned short* deltab = (unsigned short*)(ws);             // 8M   d6..d9
    unsigned short* gb     = (unsigned short*)(ws + 8388608);   // 8M   d2..d9
    float*          xp     = (float*)(ws + 25165824);           // 1.25M d5..d9
    unsigned short* drb    = (unsigned short*)(ws + 27262976);  // 512K d5..d6
    float*          P8     = (float*)(ws + 27787264);           // 10.5M d4..d5
    unsigned short* cdb    = (unsigned short*)(ws + 33554432);  // 8M   d7..d9
    float*          Sbuf   = (float*)(ws + 41943040);           // 16.78M d7..d9
    unsigned short* wInT   = (unsigned short*)(ws + 50331648);  // 8M   d1..d2
    unsigned short* hb     = (unsigned short*)(ws + 58720256);  // 4M   d1..d2
    unsigned short* wOutT  = (unsigned short*)(ws + 62914560);  // 4M   d1..d10
    unsigned short* xsb    = (unsigned short*)(ws + 67108864);  // 8M   d3..d7
    unsigned short* yb     = (unsigned short*)(ws + 67108864);  // 8M   d9..d10
    unsigned short* wXT    = (unsigned short*)(ws + 75497472);  // 640K d1..d4
    unsigned short* dtwT   = (unsigned short*)(ws + 76152832);  // 512K d1..d6

    // d1. LN + all four weight transposes, one dispatch
    prep<<<3744, 256, 0, stream>>>(x, norm_w, norm_b, hb,
                                   in_proj_w, wInT, x_proj_w, wXT,
                                   dt_proj_w, dtwT, out_proj_w, wOutT);

    // d2. in_proj with split epilogue: xs half -> xrb bf16; gate -> gb silu bf16
    gemm_bf16<128, 128, 5><<<dim3(32, 16, 1), 256, 0, stream>>>(
        hb, wInT, (float*)xrb, MROWS, 2 * DI, DM, DM, nullptr, (const float*)gb);

    // d3. conv + silu over bf16 xr (xs half only) -> xsb bf16  [vectorized x4]
    conv_silu<<<(BSZ * LLEN * DI / 4) / 256, 256, 0, stream>>>(
        xrb, conv_w, conv_b, xsb);

    // d4. x_proj MFMA split-K=8 -> P8 partials  [640 blocks, 4 K-steps each]
    gemm_bf16<128, 32, 0><<<dim3(5, 16, SKX), 256, 0, stream>>>(
        xsb, wXT, P8, MROWS, NXP, DI, DI / SKX, nullptr, nullptr);
    // d5. reduce 8 partials -> xp fp32, drb bf16
    xproj_reduce<<<(MROWS * NXP) / 256, 256, 0, stream>>>(P8, xp, drb);

    // d6. dt_proj MFMA + softplus -> deltab bf16  [EPI=4]
    gemm_bf16<128, 64, 4><<<dim3(32, 16, 1), 256, 0, stream>>>(
        drb, dtwT, (float*)deltab, MROWS, DI, DTR, DTR, dt_proj_b, nullptr);

    // d7-d9. chunked selective scan (NCH=64, 16-step chains, 4096 blocks)
    scan_part<<<BSZ * NCH * (DI / 64), 256, 0, stream>>>(
        deltab, xsb, cdb, xp, A_log, D_param, Sbuf);
    scan_fix<<<(BSZ * DI * DS) / 256, 256, 0, stream>>>(Sbuf, cdb, A_log);
    scan_corr<<<BSZ * NCH * (DI / 64), 256, 0, stream>>>(
        deltab, cdb, xp, gb, A_log, Sbuf, yb);

    // d10. out_proj MFMA + residual -> out  [BN=64, 256 blocks — proven]
    gemm_bf16<128, 64, 2><<<dim3(16, 16, 1), 256, 0, stream>>>(
        yb, wOutT, out, MROWS, DM, DI, DI, nullptr, x);
}

// Round 16
// 196.095 us; speedup vs baseline: 1.0298x; 1.0058x over previous
//
#include <hip/hip_runtime.h>
#include <hip/hip_bf16.h>
#include <math.h>

// Problem constants
#define BSZ     2
#define LLEN    1024
#define DM      1024
#define DI      2048
#define DS      16
#define DTR     128
#define NXP     160          // DTR + 2*DS
#define MROWS   (BSZ*LLEN)   // 2048
#define NCH     64           // scan chunks
#define CHL     (LLEN/NCH)   // 16 steps per chunk
#define SKX     8            // x_proj split-K factor

typedef short  bf16x8 __attribute__((ext_vector_type(8)));   // 8 bf16 (4 VGPRs)
typedef float  f32x4  __attribute__((ext_vector_type(4)));

__device__ __forceinline__ unsigned short f2bf(float f) {
    unsigned int u = __float_as_uint(f);
    return (unsigned short)((u + 0x7FFFu + ((u >> 16) & 1u)) >> 16);   // RNE
}
__device__ __forceinline__ float bf2f(unsigned short u) {
    return __uint_as_float((unsigned int)u << 16);
}

// ---------------------------------------------------------------------------
// prep: ONE dispatch = LayerNorm->bf16 (blocks 0..2047) + 4 weight
// cast+transposes (blocks 2048..3743). fp32 src[K][N] -> bf16 dst[N][K].
// ---------------------------------------------------------------------------
__global__ __launch_bounds__(256) void prep(
    const float* __restrict__ x, const float* __restrict__ nw,
    const float* __restrict__ nbv, unsigned short* __restrict__ hb,
    const float* __restrict__ w0, unsigned short* __restrict__ t0,
    const float* __restrict__ w1, unsigned short* __restrict__ t1,
    const float* __restrict__ w2, unsigned short* __restrict__ t2,
    const float* __restrict__ w3, unsigned short* __restrict__ t3)
{
    __shared__ unsigned short t[64][68];
    __shared__ float ss[4], sq[4];
    const int tid = threadIdx.x;
    int bid = blockIdx.x;

    if (bid < 2048) {                      // ---- LayerNorm row ----
        const int r = bid;
        const float4 v = ((const float4*)(x + (size_t)r * DM))[tid];
        float s  = v.x + v.y + v.z + v.w;
        float q  = v.x*v.x + v.y*v.y + v.z*v.z + v.w*v.w;
        #pragma unroll
        for (int o = 32; o > 0; o >>= 1) {
            s += __shfl_down(s, o);
            q += __shfl_down(q, o);
        }
        if ((tid & 63) == 0) { ss[tid >> 6] = s; sq[tid >> 6] = q; }
        __syncthreads();
        s = ss[0] + ss[1] + ss[2] + ss[3];
        q = sq[0] + sq[1] + sq[2] + sq[3];
        const float mu  = s * (1.0f / DM);
        const float var = q * (1.0f / DM) - mu * mu;
        const float rs  = rsqrtf(var + 1e-5f);
        const float4 wv = ((const float4*)nw)[tid];
        const float4 bv = ((const float4*)nbv)[tid];
        ushort4 ob;
        ob.x = f2bf((v.x - mu) * rs * wv.x + bv.x);
        ob.y = f2bf((v.y - mu) * rs * wv.y + bv.y);
        ob.z = f2bf((v.z - mu) * rs * wv.z + bv.z);
        ob.w = f2bf((v.w - mu) * rs * wv.w + bv.w);
        *(ushort4*)&hb[(size_t)r * DM + (tid << 2)] = ob;
        return;
    }
    bid -= 2048;                           // ---- transposes ----
    const float* src; unsigned short* dst; int K, N, bx, by;
    if (bid < 1024)      { src = w0; dst = t0; K = 1024; N = 4096;
                           bx = bid & 63; by = bid >> 6; }
    else if (bid < 1120) { int lb = bid - 1024; src = w1; dst = t1;
                           K = 2048; N = 160; bx = lb % 3; by = lb / 3; }
    else if (bid < 1184) { int lb = bid - 1120; src = w2; dst = t2;
                           K = 128; N = 2048; bx = lb & 31; by = lb >> 5; }
    else                 { int lb = bid - 1184; src = w3; dst = t3;
                           K = 2048; N = 1024; bx = lb & 15; by = lb >> 4; }
    const int k0 = by * 64, n0 = bx * 64;
    const bool full = (k0 + 64 <= K) && (n0 + 64 <= N);
    if (full) {
        #pragma unroll
        for (int q = 0; q < 4; ++q) {
            int idx = q * 256 + tid;
            int r = idx >> 4, c = (idx & 15) * 4;
            float4 v = *(const float4*)&src[(size_t)(k0 + r) * N + n0 + c];
            t[r][c]   = f2bf(v.x); t[r][c+1] = f2bf(v.y);
            t[r][c+2] = f2bf(v.z); t[r][c+3] = f2bf(v.w);
        }
        __syncthreads();
        #pragma unroll
        for (int q = 0; q < 4; ++q) {
            int idx = q * 256 + tid;
            int r = idx >> 4, c = (idx & 15) * 4;
            ushort4 o = { t[c][r], t[c+1][r], t[c+2][r], t[c+3][r] };
            *(ushort4*)&dst[(size_t)(n0 + r) * K + k0 + c] = o;
        }
        return;
    }
    #pragma unroll
    for (int q = 0; q < 4; ++q) {
        int idx = q * 256 + tid;
        int r = idx >> 4, c = (idx & 15) * 4;
        if (k0 + r < K) {
            #pragma unroll
            for (int e = 0; e < 4; ++e)
                if (n0 + c + e < N)
                    t[r][c + e] = f2bf(src[(size_t)(k0 + r) * N + n0 + c + e]);
        }
    }
    __syncthreads();
    #pragma unroll
    for (int q = 0; q < 4; ++q) {
        int idx = q * 256 + tid;
        int r = idx >> 4, c = (idx & 15) * 4;
        if (n0 + r < N) {
            #pragma unroll
            for (int e = 0; e < 4; ++e)
                if (k0 + c + e < K)
                    dst[(size_t)(n0 + r) * K + k0 + c + e] = t[c + e][r];
        }
    }
}

// ---------------------------------------------------------------------------
// padded-LDS bf16 MFMA GEMM. 256 thr = 4 waves (2x2).
// EPI: 0 fp32 out (split-K via z, fp32 stride), 3 bf16 out (split-K via z,
//      bf16 stride), 4 softplus(acc+bias) bf16 out.
// Tile note (round-9): BN >= 64 for long-K. Split-K (round-15): halving
// K-steps/block with 2x blocks cuts barrier-stall time nearly linearly.
// ---------------------------------------------------------------------------
template<int BM, int BN, int EPI>
__global__ __launch_bounds__(256) void gemm_bf16(
    const unsigned short* __restrict__ A,
    const unsigned short* __restrict__ Bt,
    float* __restrict__ C, int M, int N, int K, int kpb,
    const float* __restrict__ bias)
{
    constexpr int LDT = 72;
    __shared__ unsigned short As[BM][LDT];
    __shared__ unsigned short Bs[BN][LDT];
    const int tid  = threadIdx.x;
    const int m0   = blockIdx.y * BM;
    const int n0   = blockIdx.x * BN;
    const int kbeg = blockIdx.z * kpb;
    const int kend = kbeg + kpb;
    float* Cw = C + (size_t)blockIdx.z * M * N;                   // fp32 stride
    unsigned short* Cs = (unsigned short*)C + (size_t)blockIdx.z * M * N; // bf16
    const int wave = tid >> 6;
    const int lane = tid & 63;
    const int wr   = (wave >> 1) * (BM / 2);
    const int wc   = (wave & 1) * (BN / 2);
    constexpr int FM = BM / 32;
    constexpr int FN = BN / 32;
    const int l15 = lane & 15;
    const int kg  = lane >> 4;

    f32x4 acc[FM][FN] = {};

    for (int kt = kbeg; kt < kend; kt += 64) {
        __syncthreads();
        #pragma unroll
        for (int q = 0; q < BM / 32; ++q) {
            int idx = q * 256 + tid;
            int r = idx >> 3, c = (idx & 7) * 8;
            *(uint4*)&As[r][c] = *(const uint4*)&A[(size_t)(m0 + r) * K + kt + c];
        }
        #pragma unroll
        for (int q = 0; q < BN / 32; ++q) {
            int idx = q * 256 + tid;
            int r = idx >> 3, c = (idx & 7) * 8;
            *(uint4*)&Bs[r][c] = *(const uint4*)&Bt[(size_t)(n0 + r) * K + kt + c];
        }
        __syncthreads();
        #pragma unroll
        for (int ks = 0; ks < 2; ++ks) {
            bf16x8 af[FM], bfr[FN];
            #pragma unroll
            for (int i = 0; i < FM; ++i)
                af[i] = *(const bf16x8*)&As[wr + i * 16 + l15][ks * 32 + kg * 8];
            #pragma unroll
            for (int j = 0; j < FN; ++j)
                bfr[j] = *(const bf16x8*)&Bs[wc + j * 16 + l15][ks * 32 + kg * 8];
            #pragma unroll
            for (int i = 0; i < FM; ++i)
                #pragma unroll
                for (int j = 0; j < FN; ++j)
                    acc[i][j] = __builtin_amdgcn_mfma_f32_16x16x32_bf16(
                        af[i], bfr[j], acc[i][j], 0, 0, 0);
        }
    }
    // C/D layout: col = lane&15, row = (lane>>4)*4 + reg   [m89-verified]
    #pragma unroll
    for (int i = 0; i < FM; ++i) {
        #pragma unroll
        for (int j = 0; j < FN; ++j) {
            const int row = m0 + wr + i * 16 + kg * 4;
            const int col = n0 + wc + j * 16 + l15;
            #pragma unroll
            for (int r = 0; r < 4; ++r) {
                float v = acc[i][j][r];
                if (EPI == 4) {
                    float t = v + bias[col];
                    v = (t > 20.f) ? t : log1pf(__expf(t));
                }
                if (EPI == 3)
                    Cs[(size_t)(row + r) * N + col] = f2bf(v);
                else if (EPI == 4)
                    ((unsigned short*)C)[(size_t)(row + r) * N + col] = f2bf(v);
                else
                    Cw[(size_t)(row + r) * N + col] = v;
            }
        }
    }
}

// ---------------------------------------------------------------------------
// in_proj split-K reduce: sum 2 bf16 partials over [2048][4096];
// cols<2048 -> xrb bf16 (raw); cols>=2048 -> gb bf16 (silu). 4 cols/thread.
// ---------------------------------------------------------------------------
__global__ __launch_bounds__(256) void inproj_reduce(
    const unsigned short* __restrict__ P, unsigned short* __restrict__ xrb,
    unsigned short* __restrict__ gb)
{
    const int q = blockIdx.x * 256 + threadIdx.x;     // < 2048*4096/4
    const int row = q >> 10;                          // 1024 quads per row
    const int col0 = (q & 1023) << 2;
    const size_t base = ((size_t)row << 12) + col0;
    const ushort4 a = *(const ushort4*)&P[base];
    const ushort4 b = *(const ushort4*)&P[base + (size_t)MROWS * 4096];
    float v[4] = { bf2f(a.x) + bf2f(b.x), bf2f(a.y) + bf2f(b.y),
                   bf2f(a.z) + bf2f(b.z), bf2f(a.w) + bf2f(b.w) };
    ushort4 o;
    if (col0 < DI) {
        o.x = f2bf(v[0]); o.y = f2bf(v[1]); o.z = f2bf(v[2]); o.w = f2bf(v[3]);
        *(ushort4*)&xrb[((size_t)row << 11) + col0] = o;
    } else {
        o.x = f2bf(v[0] / (1.f + __expf(-v[0])));
        o.y = f2bf(v[1] / (1.f + __expf(-v[1])));
        o.z = f2bf(v[2] / (1.f + __expf(-v[2])));
        o.w = f2bf(v[3] / (1.f + __expf(-v[3])));
        *(ushort4*)&gb[((size_t)row << 11) + col0 - DI] = o;
    }
}

// ---------------------------------------------------------------------------
// out_proj split-K reduce: out = P0 + P1 + x  (fp32 out). 4 cols/thread.
// ---------------------------------------------------------------------------
__global__ __launch_bounds__(256) void out_reduce(
    const unsigned short* __restrict__ P, const float* __restrict__ x,
    float* __restrict__ out)
{
    const int q = blockIdx.x * 256 + threadIdx.x;     // < 2048*1024/4
    const size_t i = (size_t)q << 2;
    const ushort4 a = *(const ushort4*)&P[i];
    const ushort4 b = *(const ushort4*)&P[i + (size_t)MROWS * DM];
    const float4 xv = *(const float4*)&x[i];
    float4 o;
    o.x = bf2f(a.x) + bf2f(b.x) + xv.x;
    o.y = bf2f(a.y) + bf2f(b.y) + xv.y;
    o.z = bf2f(a.z) + bf2f(b.z) + xv.z;
    o.w = bf2f(a.w) + bf2f(b.w) + xv.w;
    *(float4*)&out[i] = o;
}

// ---------------------------------------------------------------------------
// x_proj split-K reduce: sum SKX fp32 partials; write xp fp32 + dr bf16
// ---------------------------------------------------------------------------
__global__ __launch_bounds__(256) void xproj_reduce(
    const float* __restrict__ P, float* __restrict__ xp,
    unsigned short* __restrict__ drb)
{
    const int idx = blockIdx.x * 256 + threadIdx.x;   // < 2048*160
    float s = 0.f;
    #pragma unroll
    for (int j = 0; j < SKX; ++j)
        s += P[(size_t)j * (MROWS * NXP) + idx];
    xp[idx] = s;
    const int row = idx / NXP, col = idx - row * NXP;
    if (col < DTR) drb[(size_t)row * DTR + col] = f2bf(s);
}

// ---------------------------------------------------------------------------
// causal depthwise conv (K=4) + SiLU over bf16 xr (2048 cols). x4 vectorized.
// ---------------------------------------------------------------------------
__global__ __launch_bounds__(256) void conv_silu(
    const unsigned short* __restrict__ xrb, const float* __restrict__ cw,
    const float* __restrict__ cb, unsigned short* __restrict__ xsb)
{
    const int idx = blockIdx.x * 256 + threadIdx.x;   // over 2*1024*512 quads
    const int d0 = (idx & 511) << 2;
    const int t  = (idx >> 9) & (LLEN - 1);
    const int b  = idx >> 19;
    float4 wv[4];
    #pragma unroll
    for (int e = 0; e < 4; ++e) wv[e] = ((const float4*)cw)[d0 + e];
    float acc[4];
    #pragma unroll
    for (int e = 0; e < 4; ++e) acc[e] = cb[d0 + e];
    #pragma unroll
    for (int k = 0; k < 4; ++k) {
        const int tt = t + k - 3;
        if (tt >= 0) {
            const ushort4 xv = *(const ushort4*)
                &xrb[((size_t)(b * LLEN + tt) << 11) + d0];
            acc[0] = fmaf((&wv[0].x)[k], bf2f(xv.x), acc[0]);
            acc[1] = fmaf((&wv[1].x)[k], bf2f(xv.y), acc[1]);
            acc[2] = fmaf((&wv[2].x)[k], bf2f(xv.z), acc[2]);
            acc[3] = fmaf((&wv[3].x)[k], bf2f(xv.w), acc[3]);
        }
    }
    ushort4 o;
    o.x = f2bf(acc[0] / (1.f + __expf(-acc[0])));
    o.y = f2bf(acc[1] / (1.f + __expf(-acc[1])));
    o.z = f2bf(acc[2] / (1.f + __expf(-acc[2])));
    o.w = f2bf(acc[3] / (1.f + __expf(-acc[3])));
    *(ushort4*)&xsb[((size_t)(b * LLEN + t) << 11) + d0] = o;
}

// ---------------------------------------------------------------------------
// Scan pass A: 4 threads/channel (4 states each). NCH=64 chunks of 16.
// ---------------------------------------------------------------------------
__global__ __launch_bounds__(256) void scan_part(
    unsigned short* __restrict__ dio, const unsigned short* __restrict__ ub,
    unsigned short* __restrict__ cd, const float* __restrict__ xp,
    const float* __restrict__ A_log, const float* __restrict__ Dp,
    float* __restrict__ S)
{
    const int blk  = blockIdx.x;               // 4096
    const int dgrp = blk & 31;
    const int j    = (blk >> 5) & (NCH - 1);
    const int b    = blk >> 11;
    const int c    = threadIdx.x >> 2;
    const int sg   = threadIdx.x & 3;
    const int d    = dgrp * 64 + c;
    const int nb   = sg * 4;
    float aL[4], h[4];
    #pragma unroll
    for (int n = 0; n < 4; ++n) {
        aL[n] = -__expf(A_log[d * DS + nb + n]) * 1.44269504088896f;
        h[n] = 0.f;
    }
    const float Dd = Dp[d];
    float sd = 0.f;
    const int t0 = j * CHL;
    for (int t = t0; t < t0 + CHL; ++t) {
        const size_t row = (size_t)(b * LLEN + t);
        const float dlt = bf2f(dio[row * DI + d]);
        const float u   = bf2f(ub[row * DI + d]);
        const float du  = dlt * u;
        sd += dlt;
        const float* Bp = &xp[row * NXP + DTR + nb];
        const float* Cp = &xp[row * NXP + DTR + DS + nb];
        float y = sg ? 0.f : Dd * u;
        #pragma unroll
        for (int n = 0; n < 4; ++n) {
            const float dA = exp2f(dlt * aL[n]);
            h[n] = fmaf(dA, h[n], du * Bp[n]);
            y = fmaf(h[n], Cp[n], y);
        }
        y += __shfl_xor(y, 1);
        y += __shfl_xor(y, 2);
        if (!sg) {
            dio[row * DI + d] = f2bf(y);
            cd[row * DI + d]  = f2bf(sd);
        }
    }
    float* So = &S[(((size_t)j * BSZ + b) * DI + d) * DS + nb];
    #pragma unroll
    for (int n = 0; n < 4; ++n) So[n] = h[n];
}

// ---------------------------------------------------------------------------
// Scan pass B: inter-chunk fix-up, thread per (b,d,n).
// ---------------------------------------------------------------------------
__global__ __launch_bounds__(256) void scan_fix(
    float* __restrict__ S, const unsigned short* __restrict__ cumD,
    const float* __restrict__ A_log)
{
    const int c = blockIdx.x * 256 + threadIdx.x;
    const int n = c & 15;
    const int d = (c >> 4) & (DI - 1);
    const int b = c >> 15;
    const float aL = -__expf(A_log[d * DS + n]) * 1.44269504088896f;
    float h = 0.f;
    #pragma unroll 8
    for (int j = 0; j < NCH; ++j) {
        const float sd = bf2f(cumD[(size_t)(b * LLEN + j * CHL + CHL - 1) * DI + d]);
        const size_t base = (((size_t)j * BSZ + b) * DI + d) * DS + n;
        const float Pj = exp2f(aL * sd);
        const float Sj = S[base];
        S[base] = h;
        h = fmaf(Pj, h, Sj);
    }
}

// ---------------------------------------------------------------------------
// Scan pass C (correction): 4 threads/channel. yb = bf16((y'+corr)*g)
// ---------------------------------------------------------------------------
__global__ __launch_bounds__(256) void scan_corr(
    const unsigned short* __restrict__ yp, const unsigned short* __restrict__ cumD,
    const float* __restrict__ xp, const unsigned short* __restrict__ gb,
    const float* __restrict__ A_log, const float* __restrict__ H0,
    unsigned short* __restrict__ yb)
{
    const int blk  = blockIdx.x;               // 4096
    const int dgrp = blk & 31;
    const int j    = (blk >> 5) & (NCH - 1);
    const int b    = blk >> 11;
    const int c    = threadIdx.x >> 2;
    const int sg   = threadIdx.x & 3;
    const int d    = dgrp * 64 + c;
    const int nb   = sg * 4;
    float aL[4], H[4];
    const float* Hp = &H0[(((size_t)j * BSZ + b) * DI + d) * DS + nb];
    #pragma unroll
    for (int n = 0; n < 4; ++n) {
        aL[n] = -__expf(A_log[d * DS + nb + n]) * 1.44269504088896f;
        H[n] = Hp[n];
    }
    const int t0 = j * CHL;
    for (int t = t0; t < t0 + CHL; ++t) {
        const size_t row = (size_t)(b * LLEN + t);
        const float cdv = bf2f(cumD[row * DI + d]);
        const float* Cp = &xp[row * NXP + DTR + DS + nb];
        float corr = 0.f;
        #pragma unroll
        for (int n = 0; n < 4; ++n)
            corr = fmaf(H[n] * exp2f(aL[n] * cdv), Cp[n], corr);
        corr += __shfl_xor(corr, 1);
        corr += __shfl_xor(corr, 2);
        if (!sg) {
            const float y = bf2f(yp[row * DI + d]) + corr;
            yb[row * DI + d] = f2bf(y * bf2f(gb[row * DI + d]));
        }
    }
}

// ---------------------------------------------------------------------------
extern "C" void kernel_launch(void* const* d_in, const int* in_sizes, int n_in,
                              void* d_out, int out_size, void* d_ws, size_t ws_size,
                              hipStream_t stream)
{
    (void)in_sizes; (void)n_in; (void)out_size; (void)ws_size;
    const float* x         = (const float*)d_in[0];
    const float* norm_w    = (const float*)d_in[1];
    const float* norm_b    = (const float*)d_in[2];
    const float* in_proj_w = (const float*)d_in[3];   // (1024, 4096)
    const float* conv_w    = (const float*)d_in[4];
    const float* conv_b    = (const float*)d_in[5];
    const float* x_proj_w  = (const float*)d_in[6];   // (2048, 160)
    const float* dt_proj_w = (const float*)d_in[7];   // (128, 2048)
    const float* dt_proj_b = (const float*)d_in[8];
    const float* A_log     = (const float*)d_in[9];
    const float* D_param   = (const float*)d_in[10];
    const float* out_proj_w= (const float*)d_in[11];  // (2048, 1024)
    float* out = (float*)d_out;

    // Workspace overlays (per-dispatch liveness audited):
    //   d1  prep:       writes hb, wInT, wXT, dtwT, wOutT
    //   d2  in_proj SK2: hb,wInT -> Pin bf16 [16.78M, 50.33M)
    //   d2r inproj_reduce: Pin -> xrb(0..8M) + gb(8.39M, silu)
    //   d3  conv:       xrb -> xsb(67.1M)
    //   d4  x_proj SK8: xsb,wXT -> P8(27.79M..38.27M)
    //   d5  xproj_reduce: P8 -> xp(25.2M), drb(27.26M)
    //   d6  dt_proj:    drb,dtwT -> deltab bf16 (0..8M; xrb dead after d3)
    //   d7  scan_part:  deltab(in-place y'), xsb, xp -> cdb(33.5M), Sbuf(41.94M)
    //   d8  scan_fix:   Sbuf, cdb
    //   d9  scan_corr:  deltab,cdb,xp,gb,Sbuf -> yb(67.1M over dead xsb)
    //   d10 out_proj SK2: yb,wOutT -> Pout bf16 (0..8M; deltab dead)
    //   d11 out_reduce: Pout + x -> out
    char* ws = (char*)d_ws;
    unsigned short* xrb    = (unsigned short*)(ws);             // 8M   d2r..d3
    unsigned short* deltab = (unsigned short*)(ws);             // 8M   d6..d9
    unsigned short* Pout   = (unsigned short*)(ws);             // 8M   d10..d11
    unsigned short* gb     = (unsigned short*)(ws + 8388608);   // 8M   d2r..d9
    unsigned short* Pin    = (unsigned short*)(ws + 16777216);  // 32M  d2..d2r
    float*          xp     = (float*)(ws + 25165824);           // 1.25M d5..d9
    unsigned short* drb    = (unsigned short*)(ws + 27262976);  // 512K d5..d6
    float*          P8     = (float*)(ws + 27787264);           // 10.5M d4..d5
    unsigned short* cdb    = (unsigned short*)(ws + 33554432);  // 8M   d7..d9
    float*          Sbuf   = (float*)(ws + 41943040);           // 16.78M d7..d9
    unsigned short* wInT   = (unsigned short*)(ws + 50331648);  // 8M   d1..d2
    unsigned short* hb     = (unsigned short*)(ws + 58720256);  // 4M   d1..d2
    unsigned short* wOutT  = (unsigned short*)(ws + 62914560);  // 4M   d1..d10
    unsigned short* xsb    = (unsigned short*)(ws + 67108864);  // 8M   d3..d7
    unsigned short* yb     = (unsigned short*)(ws + 67108864);  // 8M   d9..d10
    unsigned short* wXT    = (unsigned short*)(ws + 75497472);  // 640K d1..d4
    unsigned short* dtwT   = (unsigned short*)(ws + 76152832);  // 512K d1..d6

    // d1. LN + all four weight transposes, one dispatch
    prep<<<3744, 256, 0, stream>>>(x, norm_w, norm_b, hb,
                                   in_proj_w, wInT, x_proj_w, wXT,
                                   dt_proj_w, dtwT, out_proj_w, wOutT);

    // d2. in_proj split-K=2 -> Pin bf16 partials [1024 blocks, 8 K-steps]
    gemm_bf16<128, 128, 3><<<dim3(32, 16, 2), 256, 0, stream>>>(
        hb, wInT, (float*)Pin, MROWS, 2 * DI, DM, DM / 2, nullptr);
    // d2r. reduce partials -> xrb (raw) + gb (silu gate)
    inproj_reduce<<<(MROWS * 4096 / 4) / 256, 256, 0, stream>>>(Pin, xrb, gb);

    // d3. conv + silu -> xsb bf16
    conv_silu<<<(BSZ * LLEN * DI / 4) / 256, 256, 0, stream>>>(
        xrb, conv_w, conv_b, xsb);

    // d4. x_proj split-K=8 -> P8 fp32 partials [640 blocks, 4 K-steps]
    gemm_bf16<128, 32, 0><<<dim3(5, 16, SKX), 256, 0, stream>>>(
        xsb, wXT, P8, MROWS, NXP, DI, DI / SKX, nullptr);
    // d5. reduce -> xp fp32, drb bf16
    xproj_reduce<<<(MROWS * NXP) / 256, 256, 0, stream>>>(P8, xp, drb);

    // d6. dt_proj + softplus -> deltab bf16 [512 blocks, 2 K-steps]
    gemm_bf16<128, 64, 4><<<dim3(32, 16, 1), 256, 0, stream>>>(
        drb, dtwT, (float*)deltab, MROWS, DI, DTR, DTR, dt_proj_b);

    // d7-d9. chunked selective scan (NCH=64)
    scan_part<<<BSZ * NCH * (DI / 64), 256, 0, stream>>>(
        deltab, xsb, cdb, xp, A_log, D_param, Sbuf);
    scan_fix<<<(BSZ * DI * DS) / 256, 256, 0, stream>>>(Sbuf, cdb, A_log);
    scan_corr<<<BSZ * NCH * (DI / 64), 256, 0, stream>>>(
        deltab, cdb, xp, gb, A_log, Sbuf, yb);

    // d10. out_proj split-K=2 -> Pout bf16 partials [512 blocks, 16 K-steps]
    gemm_bf16<128, 64, 3><<<dim3(16, 16, 2), 256, 0, stream>>>(
        yb, wOutT, (float*)Pout, MROWS, DM, DI, DI / 2, nullptr);
    // d11. reduce + residual -> out fp32
    out_reduce<<<(MROWS * DM / 4) / 256, 256, 0, stream>>>(Pout, x, out);
}